// Round 7
// baseline (660.787 us; speedup 1.0000x reference)
//
#include <hip/hip_runtime.h>
#include <cstdint>
#include <cstddef>

typedef unsigned short u16;
typedef unsigned int u32;
typedef __attribute__((ext_vector_type(2))) unsigned int u32x2;
typedef __attribute__((ext_vector_type(2))) unsigned short u16x2;
typedef __attribute__((ext_vector_type(4))) unsigned short u16x4;
typedef __attribute__((ext_vector_type(8))) unsigned short u16x8;
typedef __attribute__((ext_vector_type(8))) __bf16 bf16x8;
typedef __attribute__((ext_vector_type(4))) float f32x4;

#define PREP_F32   0
#define PREP_BF16  1   // row-major bf16 [N][128]
#define PREP_LN    2
#define PREP_BF16S 3   // slice-major bf16 [8][N][16]
#define EPI_IN    0   // y = relu(xW + b)                -> bf16 row-major
#define EPI_SCALE 1   // y = inv[r]*(xW + b)             -> bf16 SLICE-major
#define EPI_LNRES 2   // y = relu(LN(xW + b + res))      -> bf16 row-major
#define EPI_NONE  3   // y = xW + b                      -> fp32 (NOUT=64)

__device__ __forceinline__ float wred(float v) {
#pragma unroll
  for (int m = 32; m >= 1; m >>= 1) v += __shfl_xor(v, m, 64);
  return v;
}
__device__ __forceinline__ u16 f2bf(float f) {
  u32 u = __float_as_uint(f);
  u += 0x7fffu + ((u >> 16) & 1u);
  return (u16)(u >> 16);
}
__device__ __forceinline__ float bflo(u32 u) { return __uint_as_float(u << 16); }
__device__ __forceinline__ float bfhi(u32 u) { return __uint_as_float(u & 0xffff0000u); }
__device__ __forceinline__ u32 pack2(float a, float b) {
  u32 ua = __float_as_uint(a); ua += 0x7fffu + ((ua >> 16) & 1u);
  u32 ub = __float_as_uint(b); ub += 0x7fffu + ((ub >> 16) & 1u);
  return (ua >> 16) | (ub & 0xffff0000u);
}

// ---------------- CSR build: hierarchical exclusive scan of int(degree) ----
__global__ void scan_block_k(const float* __restrict__ deg, int* __restrict__ offs,
                             int* __restrict__ bsum, int N) {
  __shared__ int sh[256];
  int tid = threadIdx.x;
  int i = blockIdx.x * 256 + tid;
  int c = (i < N) ? (int)(deg[i] + 0.5f) : 0;
  int val = c;
  for (int off = 1; off < 256; off <<= 1) {
    sh[tid] = val; __syncthreads();
    if (tid >= off) val += sh[tid - off];
    __syncthreads();
  }
  if (i < N) offs[i] = val - c;
  if (tid == 255) bsum[blockIdx.x] = val;
}

__global__ void scan_bsum_k(int* __restrict__ bsum, int nb) {
  __shared__ int sh[1024];
  int tid = threadIdx.x;
  int c = (tid < nb) ? bsum[tid] : 0;
  int val = c;
  for (int off = 1; off < 1024; off <<= 1) {
    sh[tid] = val; __syncthreads();
    if (tid >= off) val += sh[tid - off];
    __syncthreads();
  }
  if (tid < nb) bsum[tid] = val - c;
}

__global__ void scan_add_k(int* __restrict__ offs, const int* __restrict__ bsum,
                           int* __restrict__ gcur, float* __restrict__ inv,
                           const float* __restrict__ deg, int N, int E) {
  int i = blockIdx.x * 256 + threadIdx.x;
  if (i < N) {
    int o = offs[i] + bsum[i >> 8];
    offs[i] = o;
    inv[i] = rsqrtf(deg[i] + 1.0f);
    if ((i & 511) == 0) gcur[i >> 9] = o;   // bucket claim cursor = bucket base
  } else if (i == N) {
    offs[N] = E;
  }
}

// ---- phase C: bucket-scatter edges into (src,dst) pairs, bucket = dst>>9 ----
__global__ __launch_bounds__(256) void scatter_k(
    const int* __restrict__ src, const int* __restrict__ dst,
    int* __restrict__ gcur, uint2* __restrict__ pairs, int E) {
  __shared__ int hist[256];
  __shared__ int base_[256];
  const int tid = threadIdx.x;
  const int e0 = blockIdx.x * 8192;
  const int e1 = min(E, e0 + 8192);
  hist[tid] = 0;
  __syncthreads();
  for (int e = e0 + tid; e < e1; e += 256)
    atomicAdd(&hist[dst[e] >> 9], 1);
  __syncthreads();
  int c = hist[tid];
  if (c > 0) base_[tid] = atomicAdd(&gcur[tid], c);
  hist[tid] = 0;
  __syncthreads();
  for (int e = e0 + tid; e < e1; e += 256) {
    int d = dst[e];
    int b = d >> 9;
    int r = atomicAdd(&hist[b], 1);
    pairs[base_[b] + r] = make_uint2((u32)src[e], (u32)d);
  }
}

// ---- phase D: per-bucket CSR fill, cursors in LDS, col window L2-resident ----
__global__ __launch_bounds__(256) void fill2_k(
    const uint2* __restrict__ pairs, const int* __restrict__ offs,
    int* __restrict__ col, int N) {
  __shared__ int cur[512];
  const int b = blockIdx.x;
  const int n0 = b << 9;
  const int n1 = min(N, n0 + 512);
  const int tid = threadIdx.x;
  for (int i = tid; i < n1 - n0; i += 256) cur[i] = offs[n0 + i];
  __syncthreads();
  const int e0 = offs[n0], e1 = offs[n1];
  for (int e = e0 + tid; e < e1; e += 256) {
    uint2 pr = pairs[e];
    int p = atomicAdd(&cur[(int)pr.y - n0], 1);
    col[p] = (int)pr.x;
  }
}

// ---------------- SpMM, feature-sliced & XCD-pinned ------------------------
// msc2/agg2 layout: u32x2 [8][N][4]  (32 B per node per slice)
// slice = blockIdx % 8  -> lands on XCD (slice) under round-robin dispatch,
// so each XCD's gathers hit its own L2-resident 3.2 MB slice.
// Wave: 8 consecutive dst rows x 2 edge slots x 4 feature lanes (8B each).
__global__ __launch_bounds__(256) void spmm_k(
    const u32x2* __restrict__ msc2, const int* __restrict__ offs,
    const int* __restrict__ col, const float* __restrict__ inv,
    u32x2* __restrict__ agg2, int N) {
  const int s = blockIdx.x & 7;
  const int chunk = blockIdx.x >> 3;
  const int lane = threadIdx.x & 63, wid = threadIdx.x >> 6;
  const int r3 = lane >> 3;          // row in wave's 8-row group
  const int e  = (lane >> 2) & 1;    // edge slot
  const int f  = lane & 3;           // 8-byte feature chunk
  const int d  = chunk * 32 + wid * 8 + r3;
  const size_t sb = (size_t)s * (size_t)N;
  const bool rowok = d < N;
  const int s0 = rowok ? offs[d] : 0;
  const int s1 = rowok ? offs[d + 1] : 0;
  const int deg = s1 - s0;
  const int last = max(s1 - 1, 0);
  float4 acc = make_float4(0.f, 0.f, 0.f, 0.f);
  for (int k = 0; __any(k < deg); k += 4) {
    int jA = s0 + k + e;
    int jB = jA + 2;
    int cA = min(jA, last);
    int cB = min(jB, last);
    int srcA = __builtin_nontemporal_load(&col[cA]);
    int srcB = __builtin_nontemporal_load(&col[cB]);
    u32x2 vA = msc2[(sb + (u32)srcA) * 4 + f];
    u32x2 vB = msc2[(sb + (u32)srcB) * 4 + f];
    float mA = (jA < s1) ? 1.f : 0.f;
    float mB = (jB < s1) ? 1.f : 0.f;
    acc.x = fmaf(mA, bflo(vA.x), acc.x); acc.y = fmaf(mA, bfhi(vA.x), acc.y);
    acc.z = fmaf(mA, bflo(vA.y), acc.z); acc.w = fmaf(mA, bfhi(vA.y), acc.w);
    acc.x = fmaf(mB, bflo(vB.x), acc.x); acc.y = fmaf(mB, bfhi(vB.x), acc.y);
    acc.z = fmaf(mB, bflo(vB.y), acc.z); acc.w = fmaf(mB, bfhi(vB.y), acc.w);
  }
  acc.x += __shfl_xor(acc.x, 4, 64);
  acc.y += __shfl_xor(acc.y, 4, 64);
  acc.z += __shfl_xor(acc.z, 4, 64);
  acc.w += __shfl_xor(acc.w, 4, 64);
  if (e == 0 && rowok) {
    u32x2 r = msc2[(sb + d) * 4 + f];   // self loop
    float iv = inv[d];
    u32x2 o;
    o.x = pack2((acc.x + bflo(r.x)) * iv, (acc.y + bfhi(r.x)) * iv);
    o.y = pack2((acc.z + bflo(r.y)) * iv, (acc.w + bfhi(r.y)) * iv);
    __builtin_nontemporal_store(o, &agg2[(sb + d) * 4 + f]);
  }
}

// ---------------- weight pre-pack: fp32 [128][ncol] -> bf16 MFMA fragments ----
__global__ void pack_w_k(const float* __restrict__ W, u16* __restrict__ P, int ncol) {
  int t = blockIdx.x * 256 + threadIdx.x;
  int NT = ncol >> 4;
  int total = 4 * NT * 64;
  if (t >= total) return;
  int lane = t & 63;
  int tmp = t >> 6;
  int nt = tmp % NT, kc = tmp / NT;
  int n = nt * 16 + (lane & 15);
  int kb = kc * 32 + ((lane >> 4) << 2);
  u16* dst = P + (size_t)t * 8;
#pragma unroll
  for (int j = 0; j < 8; ++j) {
    int k = kb + (j & 3) + ((j >> 2) << 4);
    dst[j] = f2bf(W[(size_t)k * ncol + n]);
  }
}

// ---------------- MFMA GEMM: [N,128] @ [128,NOUT] + fused prep/epilogue ------
template <int NOUT, int PREP, int EPI>
__global__ __launch_bounds__(256) void gemm_mfma(
    const void* __restrict__ Xv, const u16* __restrict__ Wp,
    const float* __restrict__ bias, void* __restrict__ Yv,
    const void* __restrict__ resv,   // inv fp32 (SCALE) or bf16 residual h (LNRES)
    const float* __restrict__ g1, const float* __restrict__ lb1,
    int N) {
  constexpr int NT = NOUT / 16;
  __shared__ union {
    u16  xs[32][136];
    float cs[32][132];
  } sh;
  const int tid = threadIdx.x;
  const int lane = tid & 63, wid = tid >> 6;
  const int row0 = blockIdx.x * 32;

  if constexpr (PREP == PREP_F32) {
    const float* X = (const float*)Xv;
    for (int i = tid; i < 1024; i += 256) {
      int r = i >> 5, c4 = i & 31;
      float4 v = ((const float4*)(X + (size_t)(row0 + r) * 128))[c4];
      u16x4 o = {f2bf(v.x), f2bf(v.y), f2bf(v.z), f2bf(v.w)};
      *(u16x4*)&sh.xs[r][c4 * 4] = o;
    }
  } else if constexpr (PREP == PREP_BF16) {
    const u16x4* X = (const u16x4*)Xv;
    for (int i = tid; i < 1024; i += 256) {
      int r = i >> 5, c4 = i & 31;
      *(u16x4*)&sh.xs[r][c4 * 4] = X[(size_t)(row0 + r) * 32 + c4];
    }
  } else if constexpr (PREP == PREP_BF16S) {
    // slice-major [8][N][4x(8B)]: feature group c4 lives in slice c4>>2, unit c4&3
    const u16x4* X = (const u16x4*)Xv;
    for (int i = tid; i < 1024; i += 256) {
      int r = i >> 5, c4 = i & 31;
      int sl = c4 >> 2, q = c4 & 3;
      *(u16x4*)&sh.xs[r][c4 * 4] = X[((size_t)sl * N + row0 + r) * 4 + q];
    }
  } else {  // PREP_LN: normalize bf16 rows with g1/lb1
    const u32* X = (const u32*)Xv;
    float2 gg = *(const float2*)&g1[lane * 2];
    float2 bb = *(const float2*)&lb1[lane * 2];
    for (int rr = 0; rr < 8; ++rr) {
      int r = wid * 8 + rr;
      u32 v = X[(size_t)(row0 + r) * 64 + lane];
      float tx = bflo(v), ty = bfhi(v);
      float mean = wred(tx + ty) * (1.f / 128.f);
      float dx = tx - mean, dy = ty - mean;
      float var = wred(dx * dx + dy * dy) * (1.f / 128.f);
      float rstd = rsqrtf(var + 1e-5f);
      u16x2 o = {f2bf(dx * rstd * gg.x + bb.x), f2bf(dy * rstd * gg.y + bb.y)};
      *(u16x2*)&sh.xs[r][lane * 2] = o;
    }
  }
  __syncthreads();

  constexpr int NTW = (NOUT == 128) ? 4 : 2;
  const int m0  = (NOUT == 128) ? ((wid >> 1) << 4) : ((wid & 1) << 4);
  const int ntb = (NOUT == 128) ? ((wid & 1) << 2) : ((wid >> 1) << 1);

  f32x4 acc[NTW];
#pragma unroll
  for (int t = 0; t < NTW; ++t) acc[t] = (f32x4){0.f, 0.f, 0.f, 0.f};

  const int ar  = m0 + (lane & 15);
  const int akb = (lane >> 4) << 2;
  const bf16x8* Bp = (const bf16x8*)Wp;
#pragma unroll
  for (int kc = 0; kc < 4; ++kc) {
    u16x4 lo = *(const u16x4*)&sh.xs[ar][kc * 32 + akb];
    u16x4 hi = *(const u16x4*)&sh.xs[ar][kc * 32 + akb + 16];
    u16x8 av;
#pragma unroll
    for (int j = 0; j < 4; ++j) { av[j] = lo[j]; av[j + 4] = hi[j]; }
    bf16x8 a = __builtin_bit_cast(bf16x8, av);
#pragma unroll
    for (int t = 0; t < NTW; ++t) {
      bf16x8 b = Bp[(kc * NT + ntb + t) * 64 + lane];
      acc[t] = __builtin_amdgcn_mfma_f32_16x16x32_bf16(a, b, acc[t], 0, 0, 0);
    }
  }

  const int cb = lane & 15;
  const int rg = (lane >> 4) << 2;
  if constexpr (EPI == EPI_NONE) {
    float* Y = (float*)Yv;
#pragma unroll
    for (int t = 0; t < NTW; ++t) {
      int col = (ntb + t) * 16 + cb;
      float bv = bias[col];
#pragma unroll
      for (int r = 0; r < 4; ++r) {
        int gr = row0 + m0 + rg + r;
        Y[(size_t)gr * NOUT + col] = acc[t][r] + bv;
      }
    }
  } else if constexpr (EPI == EPI_SCALE) {
    // slice-major bf16 output [8][N][16]
    const float* inv = (const float*)resv;
    u16* Y = (u16*)Yv;
#pragma unroll
    for (int t = 0; t < NTW; ++t) {
      int sl = ntb + t;
      float bv = bias[sl * 16 + cb];
      const size_t sbase = (size_t)sl * (size_t)N;
#pragma unroll
      for (int r = 0; r < 4; ++r) {
        int gr = row0 + m0 + rg + r;
        Y[(sbase + gr) * 16 + cb] = f2bf((acc[t][r] + bv) * inv[gr]);
      }
    }
  } else {
    // EPI_IN / EPI_LNRES: stage to cs, then row-wise epilogue, bf16 u32 stores
    __syncthreads();  // xs (union alias) may still be read by other waves
#pragma unroll
    for (int t = 0; t < NTW; ++t) {
      int col = (ntb + t) * 16 + cb;
      float bv = bias[col];
#pragma unroll
      for (int r = 0; r < 4; ++r) sh.cs[m0 + rg + r][col] = acc[t][r] + bv;
    }
    __syncthreads();
    u32* Y = (u32*)Yv;
    if constexpr (EPI == EPI_IN) {
      for (int rr = 0; rr < 8; ++rr) {
        int r = wid * 8 + rr;
        int gr = row0 + r;
        float2 t2 = *(const float2*)&sh.cs[r][lane * 2];
        Y[(size_t)gr * 64 + lane] = pack2(fmaxf(t2.x, 0.f), fmaxf(t2.y, 0.f));
      }
    } else {  // EPI_LNRES
      const u32* res = (const u32*)resv;
      float2 gg = *(const float2*)&g1[lane * 2];
      float2 bb = *(const float2*)&lb1[lane * 2];
      for (int rr = 0; rr < 8; ++rr) {
        int r = wid * 8 + rr;
        int gr = row0 + r;
        float2 t2 = *(const float2*)&sh.cs[r][lane * 2];
        u32 hv = res[(size_t)gr * 64 + lane];
        float tx = t2.x + bflo(hv), ty = t2.y + bfhi(hv);
        float mean = wred(tx + ty) * (1.f / 128.f);
        float dx = tx - mean, dy = ty - mean;
        float var = wred(dx * dx + dy * dy) * (1.f / 128.f);
        float rstd = rsqrtf(var + 1e-5f);
        float y0 = fmaxf(dx * rstd * gg.x + bb.x, 0.f);
        float y1 = fmaxf(dy * rstd * gg.y + bb.y, 0.f);
        Y[(size_t)gr * 64 + lane] = pack2(y0, y1);
      }
    }
  }
}

// ---------------------------------------------------------------------------
extern "C" void kernel_launch(void* const* d_in, const int* in_sizes, int n_in,
                              void* d_out, int out_size, void* d_ws, size_t ws_size,
                              hipStream_t stream) {
  (void)n_in; (void)out_size; (void)ws_size;
  const float* x      = (const float*)d_in[0];
  const int*   eidx   = (const int*)d_in[1];
  const float* degree = (const float*)d_in[2];
  const float* Win    = (const float*)d_in[3];
  const float* b_in   = (const float*)d_in[4];
  const float* W1     = (const float*)d_in[5];
  const float* b1     = (const float*)d_in[6];
  const float* W2     = (const float*)d_in[7];
  const float* b2     = (const float*)d_in[8];
  const float* ln_g   = (const float*)d_in[9];
  const float* ln_b   = (const float*)d_in[10];
  const float* out_g  = (const float*)d_in[11];
  const float* out_b  = (const float*)d_in[12];
  const float* Wout   = (const float*)d_in[13];
  const float* b_out  = (const float*)d_in[14];

  const int N = in_sizes[0] / 128;
  const int E = in_sizes[1] / 2;
  const int* esrc = eidx;
  const int* edst = eidx + E;

  char* p = (char*)d_ws;
  auto alloc = [&](size_t bytes) {
    char* q = p;
    p += (bytes + 255) & ~(size_t)255;
    return q;
  };
  float* inv    = (float*)alloc((size_t)N * 4);
  int*   offs   = (int*)alloc(((size_t)N + 1) * 4);
  int*   gcur   = (int*)alloc(256 * 4);
  int*   bsum   = (int*)alloc(1024 * 4);
  int*   col    = (int*)alloc((size_t)E * 4);
  uint2* pairs  = (uint2*)alloc((size_t)E * 8);
  u32*   h      = (u32*)alloc((size_t)N * 128 * 2);     // bf16 residual, row-major
  u32*   msc    = (u32*)alloc((size_t)N * 128 * 2);     // bf16, SLICE-major [8][N][16]
  u32*   agg    = (u32*)alloc((size_t)N * 128 * 2);     // bf16, SLICE-major [8][N][16]
  u16*   pWin   = (u16*)alloc(4 * 8 * 64 * 8 * 2);
  u16*   pWout  = (u16*)alloc(4 * 4 * 64 * 8 * 2);
  u16*   pW1    = (u16*)alloc(3 * 4 * 8 * 64 * 8 * 2);
  u16*   pW2    = (u16*)alloc(3 * 4 * 8 * 64 * 8 * 2);

  pack_w_k<<<8, 256, 0, stream>>>(Win, pWin, 128);
  for (int l = 0; l < 3; ++l) {
    pack_w_k<<<8, 256, 0, stream>>>(W1 + (size_t)l * 128 * 128, pW1 + (size_t)l * 16384, 128);
    pack_w_k<<<8, 256, 0, stream>>>(W2 + (size_t)l * 128 * 128, pW2 + (size_t)l * 16384, 128);
  }
  pack_w_k<<<4, 256, 0, stream>>>(Wout, pWout, 64);

  const int nb = (N + 255) / 256;
  const int NB = (N + 511) / 512;              // dst buckets of 512 nodes
  scan_block_k<<<nb, 256, 0, stream>>>(degree, offs, bsum, N);
  scan_bsum_k<<<1, 1024, 0, stream>>>(bsum, nb);
  scan_add_k<<<(N + 256) / 256, 256, 0, stream>>>(offs, bsum, gcur, inv, degree, N, E);
  scatter_k<<<(E + 8191) / 8192, 256, 0, stream>>>(esrc, edst, gcur, pairs, E);
  fill2_k<<<NB, 256, 0, stream>>>(pairs, offs, col, N);

  const int gemmGrid = (N + 31) / 32;
  const int CH = (N + 31) / 32;                // 32 dst rows per spmm block
  const int spmmGrid = 8 * CH;                 // slice = blockIdx % 8 (XCD-pinned)

  gemm_mfma<128, PREP_F32, EPI_IN><<<gemmGrid, 256, 0, stream>>>(
      x, pWin, b_in, h, nullptr, nullptr, nullptr, N);
  for (int l = 0; l < 3; ++l) {
    gemm_mfma<128, PREP_BF16, EPI_SCALE><<<gemmGrid, 256, 0, stream>>>(
        h, pW1 + (size_t)l * 16384, b1 + l * 128, msc, inv, nullptr, nullptr, N);
    spmm_k<<<spmmGrid, 256, 0, stream>>>(
        (const u32x2*)msc, offs, col, inv, (u32x2*)agg, N);
    gemm_mfma<128, PREP_BF16S, EPI_LNRES><<<gemmGrid, 256, 0, stream>>>(
        agg, pW2 + (size_t)l * 16384, b2 + l * 128, h, h,
        ln_g + l * 128, ln_b + l * 128, N);
  }
  gemm_mfma<64, PREP_LN, EPI_NONE><<<gemmGrid, 256, 0, stream>>>(
      h, pWout, b_out, d_out, nullptr, out_g, out_b, N);
}

// Round 8
// 391.320 us; speedup vs baseline: 1.6886x; 1.6886x over previous
//
#include <hip/hip_runtime.h>
#include <cstdint>
#include <cstddef>

typedef unsigned short u16;
typedef unsigned int u32;
typedef __attribute__((ext_vector_type(2))) unsigned short u16x2;
typedef __attribute__((ext_vector_type(4))) unsigned short u16x4;
typedef __attribute__((ext_vector_type(8))) unsigned short u16x8;
typedef __attribute__((ext_vector_type(8))) __bf16 bf16x8;
typedef __attribute__((ext_vector_type(4))) float f32x4;

#define PREP_F32   0
#define PREP_BF16  1
#define PREP_LN    2
#define EPI_IN    0   // y = relu(xW + b)        -> bf16
#define EPI_SCALE 1   // y = inv[r]*(xW + b)     -> bf16
#define EPI_NONE  3   // y = xW + b              -> fp32 (NOUT=64)

__device__ __forceinline__ float wred(float v) {
#pragma unroll
  for (int m = 32; m >= 1; m >>= 1) v += __shfl_xor(v, m, 64);
  return v;
}
__device__ __forceinline__ u16 f2bf(float f) {
  u32 u = __float_as_uint(f);
  u += 0x7fffu + ((u >> 16) & 1u);
  return (u16)(u >> 16);
}
__device__ __forceinline__ float bflo(u32 u) { return __uint_as_float(u << 16); }
__device__ __forceinline__ float bfhi(u32 u) { return __uint_as_float(u & 0xffff0000u); }
__device__ __forceinline__ u32 pack2(float a, float b) {
  u32 ua = __float_as_uint(a); ua += 0x7fffu + ((ua >> 16) & 1u);
  u32 ub = __float_as_uint(b); ub += 0x7fffu + ((ub >> 16) & 1u);
  return (ua >> 16) | (ub & 0xffff0000u);
}

// ---------------- CSR build: hierarchical exclusive scan of int(degree) ----
__global__ void scan_block_k(const float* __restrict__ deg, int* __restrict__ offs,
                             int* __restrict__ bsum, int N) {
  __shared__ int sh[256];
  int tid = threadIdx.x;
  int i = blockIdx.x * 256 + tid;
  int c = (i < N) ? (int)(deg[i] + 0.5f) : 0;
  int val = c;
  for (int off = 1; off < 256; off <<= 1) {
    sh[tid] = val; __syncthreads();
    if (tid >= off) val += sh[tid - off];
    __syncthreads();
  }
  if (i < N) offs[i] = val - c;
  if (tid == 255) bsum[blockIdx.x] = val;
}

__global__ void scan_bsum_k(int* __restrict__ bsum, int nb) {
  __shared__ int sh[1024];
  int tid = threadIdx.x;
  int c = (tid < nb) ? bsum[tid] : 0;
  int val = c;
  for (int off = 1; off < 1024; off <<= 1) {
    sh[tid] = val; __syncthreads();
    if (tid >= off) val += sh[tid - off];
    __syncthreads();
  }
  if (tid < nb) bsum[tid] = val - c;
}

__global__ void scan_add_k(int* __restrict__ offs, const int* __restrict__ bsum,
                           int* __restrict__ gcur, float* __restrict__ inv,
                           const float* __restrict__ deg, int N, int E) {
  int i = blockIdx.x * 256 + threadIdx.x;
  if (i < N) {
    int o = offs[i] + bsum[i >> 8];
    offs[i] = o;
    inv[i] = rsqrtf(deg[i] + 1.0f);
    if ((i & 511) == 0) gcur[i >> 9] = o;   // bucket claim cursor = bucket base
  } else if (i == N) {
    offs[N] = E;
  }
}

// ---- phase C: bucket-scatter edges into (src,dst) pairs, bucket = dst>>9 ----
__global__ __launch_bounds__(256) void scatter_k(
    const int* __restrict__ src, const int* __restrict__ dst,
    int* __restrict__ gcur, uint2* __restrict__ pairs, int E) {
  __shared__ int hist[256];
  __shared__ int base_[256];
  const int tid = threadIdx.x;
  const int e0 = blockIdx.x * 8192;
  const int e1 = min(E, e0 + 8192);
  hist[tid] = 0;
  __syncthreads();
  for (int e = e0 + tid; e < e1; e += 256)
    atomicAdd(&hist[dst[e] >> 9], 1);
  __syncthreads();
  int c = hist[tid];
  if (c > 0) base_[tid] = atomicAdd(&gcur[tid], c);
  hist[tid] = 0;
  __syncthreads();
  for (int e = e0 + tid; e < e1; e += 256) {
    int d = dst[e];
    int b = d >> 9;
    int r = atomicAdd(&hist[b], 1);
    pairs[base_[b] + r] = make_uint2((u32)src[e], (u32)d);
  }
}

// ---- phase D: per-bucket CSR fill, cursors in LDS, col window L2-resident ----
__global__ __launch_bounds__(256) void fill2_k(
    const uint2* __restrict__ pairs, const int* __restrict__ offs,
    int* __restrict__ col, int N) {
  __shared__ int cur[512];
  const int b = blockIdx.x;
  const int n0 = b << 9;
  const int n1 = min(N, n0 + 512);
  const int tid = threadIdx.x;
  for (int i = tid; i < n1 - n0; i += 256) cur[i] = offs[n0 + i];
  __syncthreads();
  const int e0 = offs[n0], e1 = offs[n1];
  for (int e = e0 + tid; e < e1; e += 256) {
    uint2 pr = pairs[e];
    int p = atomicAdd(&cur[(int)pr.y - n0], 1);
    col[p] = (int)pr.x;
  }
}

// ---------------- weight pre-pack, ALL matrices in one launch ---------------
// blocks 0..7: Win(128); 8..31: W1[3](128); 32..55: W2[3](128); 56..59: Wout(64)
__global__ void pack_all_k(const float* __restrict__ Win, const float* __restrict__ W1,
                           const float* __restrict__ W2, const float* __restrict__ Wout,
                           u16* __restrict__ pWin, u16* __restrict__ pW1,
                           u16* __restrict__ pW2, u16* __restrict__ pWout) {
  const int b = blockIdx.x;
  const float* W; u16* P; int ncol; int t;
  if (b < 8)       { W = Win;                        P = pWin;                      ncol = 128; t = b * 256 + threadIdx.x; }
  else if (b < 32) { int l = (b - 8) / 8;  W = W1 + (size_t)l * 16384;  P = pW1 + (size_t)l * 16384; ncol = 128; t = ((b - 8) % 8) * 256 + threadIdx.x; }
  else if (b < 56) { int l = (b - 32) / 8; W = W2 + (size_t)l * 16384;  P = pW2 + (size_t)l * 16384; ncol = 128; t = ((b - 32) % 8) * 256 + threadIdx.x; }
  else             { W = Wout;                       P = pWout;                     ncol = 64;  t = (b - 56) * 256 + threadIdx.x; }
  int NT = ncol >> 4;
  int total = 4 * NT * 64;
  if (t >= total) return;
  int lane = t & 63;
  int tmp = t >> 6;
  int nt = tmp % NT, kc = tmp / NT;
  int n = nt * 16 + (lane & 15);
  int kb = kc * 32 + ((lane >> 4) << 2);
  u16* dst = P + (size_t)t * 8;
#pragma unroll
  for (int j = 0; j < 8; ++j) {
    int k = kb + (j & 3) + ((j >> 2) << 4);
    dst[j] = f2bf(W[(size_t)k * ncol + n]);
  }
}

// ---------------- fused SpMM + W2 GEMM + residual/LN/ReLU -------------------
// Phase 1 (round-5 gather mapping): each wave aggregates 8 dst rows,
//   agg_row = inv[d]*(msc[d] + sum msc[src]), written bf16 into LDS xs.
// Phase 2: 32x128 @ 128x128 MFMA + (bias, +h residual, LN, ReLU) -> h.
__global__ __launch_bounds__(256) void spmm_gemm_k(
    const uint4* __restrict__ msc, const int* __restrict__ offs,
    const int* __restrict__ col, const float* __restrict__ inv,
    const u16* __restrict__ Wp, const float* __restrict__ bias,
    u32* __restrict__ h, const float* __restrict__ g1,
    const float* __restrict__ lb1, int N) {
  __shared__ union {
    u16  xs[32][136];
    float cs[32][132];
  } sh;
  const int tid = threadIdx.x;
  const int lane = tid & 63, wid = tid >> 6;
  const int row0 = blockIdx.x * 32;
  const int g = lane >> 4, c = lane & 15;

  // ---- phase 1: aggregate 8 rows per wave into xs ----
  for (int rr = 0; rr < 8; ++rr) {
    const int d = row0 + wid * 8 + rr;
    const int s0 = offs[d], s1 = offs[d + 1];
    float2 a0 = {0.f, 0.f}, a1 = {0.f, 0.f}, a2 = {0.f, 0.f}, a3 = {0.f, 0.f};
    int base = s0;
    const int nfull = s0 + ((s1 - s0) & ~15);
    for (; base < nfull; base += 16) {
      int sA = col[base + g];
      int sB = col[base + 4 + g];
      int sC = col[base + 8 + g];
      int sD = col[base + 12 + g];
      uint4 rA = msc[(size_t)sA * 16 + c];
      uint4 rB = msc[(size_t)sB * 16 + c];
      uint4 rC = msc[(size_t)sC * 16 + c];
      uint4 rD = msc[(size_t)sD * 16 + c];
      a0.x += bflo(rA.x); a0.y += bfhi(rA.x);
      a1.x += bflo(rA.y); a1.y += bfhi(rA.y);
      a2.x += bflo(rA.z); a2.y += bfhi(rA.z);
      a3.x += bflo(rA.w); a3.y += bfhi(rA.w);
      a0.x += bflo(rB.x); a0.y += bfhi(rB.x);
      a1.x += bflo(rB.y); a1.y += bfhi(rB.y);
      a2.x += bflo(rB.z); a2.y += bfhi(rB.z);
      a3.x += bflo(rB.w); a3.y += bfhi(rB.w);
      a0.x += bflo(rC.x); a0.y += bfhi(rC.x);
      a1.x += bflo(rC.y); a1.y += bfhi(rC.y);
      a2.x += bflo(rC.z); a2.y += bfhi(rC.z);
      a3.x += bflo(rC.w); a3.y += bfhi(rC.w);
      a0.x += bflo(rD.x); a0.y += bfhi(rD.x);
      a1.x += bflo(rD.y); a1.y += bfhi(rD.y);
      a2.x += bflo(rD.z); a2.y += bfhi(rD.z);
      a3.x += bflo(rD.w); a3.y += bfhi(rD.w);
    }
    if (base < s1) {
      const int last = s1 - 1;
      int jA = base + g, jB = base + 4 + g, jC = base + 8 + g, jD = base + 12 + g;
      int sA = col[min(jA, last)];
      int sB = col[min(jB, last)];
      int sC = col[min(jC, last)];
      int sD = col[min(jD, last)];
      uint4 rA = msc[(size_t)sA * 16 + c];
      uint4 rB = msc[(size_t)sB * 16 + c];
      uint4 rC = msc[(size_t)sC * 16 + c];
      uint4 rD = msc[(size_t)sD * 16 + c];
      float mA = (jA <= last) ? 1.f : 0.f;
      float mB = (jB <= last) ? 1.f : 0.f;
      float mC = (jC <= last) ? 1.f : 0.f;
      float mD = (jD <= last) ? 1.f : 0.f;
      a0.x = fmaf(mA, bflo(rA.x), a0.x); a0.y = fmaf(mA, bfhi(rA.x), a0.y);
      a1.x = fmaf(mA, bflo(rA.y), a1.x); a1.y = fmaf(mA, bfhi(rA.y), a1.y);
      a2.x = fmaf(mA, bflo(rA.z), a2.x); a2.y = fmaf(mA, bfhi(rA.z), a2.y);
      a3.x = fmaf(mA, bflo(rA.w), a3.x); a3.y = fmaf(mA, bfhi(rA.w), a3.y);
      a0.x = fmaf(mB, bflo(rB.x), a0.x); a0.y = fmaf(mB, bfhi(rB.x), a0.y);
      a1.x = fmaf(mB, bflo(rB.y), a1.x); a1.y = fmaf(mB, bfhi(rB.y), a1.y);
      a2.x = fmaf(mB, bflo(rB.z), a2.x); a2.y = fmaf(mB, bfhi(rB.z), a2.y);
      a3.x = fmaf(mB, bflo(rB.w), a3.x); a3.y = fmaf(mB, bfhi(rB.w), a3.y);
      a0.x = fmaf(mC, bflo(rC.x), a0.x); a0.y = fmaf(mC, bfhi(rC.x), a0.y);
      a1.x = fmaf(mC, bflo(rC.y), a1.x); a1.y = fmaf(mC, bfhi(rC.y), a1.y);
      a2.x = fmaf(mC, bflo(rC.z), a2.x); a2.y = fmaf(mC, bfhi(rC.z), a2.y);
      a3.x = fmaf(mC, bflo(rC.w), a3.x); a3.y = fmaf(mC, bfhi(rC.w), a3.y);
      a0.x = fmaf(mD, bflo(rD.x), a0.x); a0.y = fmaf(mD, bfhi(rD.x), a0.y);
      a1.x = fmaf(mD, bflo(rD.y), a1.x); a1.y = fmaf(mD, bfhi(rD.y), a1.y);
      a2.x = fmaf(mD, bflo(rD.z), a2.x); a2.y = fmaf(mD, bfhi(rD.z), a2.y);
      a3.x = fmaf(mD, bflo(rD.w), a3.x); a3.y = fmaf(mD, bfhi(rD.w), a3.y);
    }
    a0.x += __shfl_xor(a0.x, 16, 64); a0.x += __shfl_xor(a0.x, 32, 64);
    a0.y += __shfl_xor(a0.y, 16, 64); a0.y += __shfl_xor(a0.y, 32, 64);
    a1.x += __shfl_xor(a1.x, 16, 64); a1.x += __shfl_xor(a1.x, 32, 64);
    a1.y += __shfl_xor(a1.y, 16, 64); a1.y += __shfl_xor(a1.y, 32, 64);
    a2.x += __shfl_xor(a2.x, 16, 64); a2.x += __shfl_xor(a2.x, 32, 64);
    a2.y += __shfl_xor(a2.y, 16, 64); a2.y += __shfl_xor(a2.y, 32, 64);
    a3.x += __shfl_xor(a3.x, 16, 64); a3.x += __shfl_xor(a3.x, 32, 64);
    a3.y += __shfl_xor(a3.y, 16, 64); a3.y += __shfl_xor(a3.y, 32, 64);
    if (g == 0) {
      uint4 r = msc[(size_t)d * 16 + c];   // self loop
      float iv = inv[d];
      uint4 o;
      o.x = pack2((a0.x + bflo(r.x)) * iv, (a0.y + bfhi(r.x)) * iv);
      o.y = pack2((a1.x + bflo(r.y)) * iv, (a1.y + bfhi(r.y)) * iv);
      o.z = pack2((a2.x + bflo(r.z)) * iv, (a2.y + bfhi(r.z)) * iv);
      o.w = pack2((a3.x + bflo(r.w)) * iv, (a3.y + bfhi(r.w)) * iv);
      *(uint4*)&sh.xs[wid * 8 + rr][c * 8] = o;
    }
  }
  __syncthreads();

  // ---- phase 2: MFMA 32x128 @ 128x128 ----
  const int m0  = (wid >> 1) << 4;
  const int ntb = (wid & 1) << 2;
  f32x4 acc[4];
#pragma unroll
  for (int t = 0; t < 4; ++t) acc[t] = (f32x4){0.f, 0.f, 0.f, 0.f};
  const int ar  = m0 + (lane & 15);
  const int akb = (lane >> 4) << 2;
  const bf16x8* Bp = (const bf16x8*)Wp;
#pragma unroll
  for (int kc = 0; kc < 4; ++kc) {
    u16x4 lo = *(const u16x4*)&sh.xs[ar][kc * 32 + akb];
    u16x4 hi = *(const u16x4*)&sh.xs[ar][kc * 32 + akb + 16];
    u16x8 av;
#pragma unroll
    for (int j = 0; j < 4; ++j) { av[j] = lo[j]; av[j + 4] = hi[j]; }
    bf16x8 a = __builtin_bit_cast(bf16x8, av);
#pragma unroll
    for (int t = 0; t < 4; ++t) {
      bf16x8 b = Bp[(kc * 8 + ntb + t) * 64 + lane];
      acc[t] = __builtin_amdgcn_mfma_f32_16x16x32_bf16(a, b, acc[t], 0, 0, 0);
    }
  }

  // ---- epilogue: bias + residual + LN + ReLU -> h (bf16) ----
  const int cb = lane & 15;
  const int rg = (lane >> 4) << 2;
  __syncthreads();  // xs no longer needed
#pragma unroll
  for (int t = 0; t < 4; ++t) {
    int colm = (ntb + t) * 16 + cb;
    float bv = bias[colm];
#pragma unroll
    for (int r = 0; r < 4; ++r) sh.cs[m0 + rg + r][colm] = acc[t][r] + bv;
  }
  __syncthreads();
  float2 gg = *(const float2*)&g1[lane * 2];
  float2 bb = *(const float2*)&lb1[lane * 2];
  for (int rr = 0; rr < 8; ++rr) {
    int r = wid * 8 + rr;
    int gr = row0 + r;
    float2 t2 = *(const float2*)&sh.cs[r][lane * 2];
    u32 hv = h[(size_t)gr * 64 + lane];
    float tx = t2.x + bflo(hv), ty = t2.y + bfhi(hv);
    float mean = wred(tx + ty) * (1.f / 128.f);
    float dx = tx - mean, dy = ty - mean;
    float var = wred(dx * dx + dy * dy) * (1.f / 128.f);
    float rstd = rsqrtf(var + 1e-5f);
    float y0 = fmaxf(dx * rstd * gg.x + bb.x, 0.f);
    float y1 = fmaxf(dy * rstd * gg.y + bb.y, 0.f);
    h[(size_t)gr * 64 + lane] = pack2(y0, y1);
  }
}

// ---------------- MFMA GEMM: [N,128] @ [128,NOUT] + fused prep/epilogue ------
template <int NOUT, int PREP, int EPI>
__global__ __launch_bounds__(256) void gemm_mfma(
    const void* __restrict__ Xv, const u16* __restrict__ Wp,
    const float* __restrict__ bias, void* __restrict__ Yv,
    const void* __restrict__ resv,   // inv fp32 (SCALE)
    const float* __restrict__ g1, const float* __restrict__ lb1,
    int N) {
  constexpr int NT = NOUT / 16;
  __shared__ union {
    u16  xs[32][136];
    float cs[32][132];
  } sh;
  const int tid = threadIdx.x;
  const int lane = tid & 63, wid = tid >> 6;
  const int row0 = blockIdx.x * 32;

  if constexpr (PREP == PREP_F32) {
    const float* X = (const float*)Xv;
    for (int i = tid; i < 1024; i += 256) {
      int r = i >> 5, c4 = i & 31;
      float4 v = ((const float4*)(X + (size_t)(row0 + r) * 128))[c4];
      u16x4 o = {f2bf(v.x), f2bf(v.y), f2bf(v.z), f2bf(v.w)};
      *(u16x4*)&sh.xs[r][c4 * 4] = o;
    }
  } else if constexpr (PREP == PREP_BF16) {
    const u16x4* X = (const u16x4*)Xv;
    for (int i = tid; i < 1024; i += 256) {
      int r = i >> 5, c4 = i & 31;
      *(u16x4*)&sh.xs[r][c4 * 4] = X[(size_t)(row0 + r) * 32 + c4];
    }
  } else {  // PREP_LN: normalize bf16 rows with g1/lb1
    const u32* X = (const u32*)Xv;
    float2 gg = *(const float2*)&g1[lane * 2];
    float2 bb = *(const float2*)&lb1[lane * 2];
    for (int rr = 0; rr < 8; ++rr) {
      int r = wid * 8 + rr;
      u32 v = X[(size_t)(row0 + r) * 64 + lane];
      float tx = bflo(v), ty = bfhi(v);
      float mean = wred(tx + ty) * (1.f / 128.f);
      float dx = tx - mean, dy = ty - mean;
      float var = wred(dx * dx + dy * dy) * (1.f / 128.f);
      float rstd = rsqrtf(var + 1e-5f);
      u16x2 o = {f2bf(dx * rstd * gg.x + bb.x), f2bf(dy * rstd * gg.y + bb.y)};
      *(u16x2*)&sh.xs[r][lane * 2] = o;
    }
  }
  __syncthreads();

  constexpr int NTW = (NOUT == 128) ? 4 : 2;
  const int m0  = (NOUT == 128) ? ((wid >> 1) << 4) : ((wid & 1) << 4);
  const int ntb = (NOUT == 128) ? ((wid & 1) << 2) : ((wid >> 1) << 1);

  f32x4 acc[NTW];
#pragma unroll
  for (int t = 0; t < NTW; ++t) acc[t] = (f32x4){0.f, 0.f, 0.f, 0.f};

  const int ar  = m0 + (lane & 15);
  const int akb = (lane >> 4) << 2;
  const bf16x8* Bp = (const bf16x8*)Wp;
#pragma unroll
  for (int kc = 0; kc < 4; ++kc) {
    u16x4 lo = *(const u16x4*)&sh.xs[ar][kc * 32 + akb];
    u16x4 hi = *(const u16x4*)&sh.xs[ar][kc * 32 + akb + 16];
    u16x8 av;
#pragma unroll
    for (int j = 0; j < 4; ++j) { av[j] = lo[j]; av[j + 4] = hi[j]; }
    bf16x8 a = __builtin_bit_cast(bf16x8, av);
#pragma unroll
    for (int t = 0; t < NTW; ++t) {
      bf16x8 b = Bp[(kc * NT + ntb + t) * 64 + lane];
      acc[t] = __builtin_amdgcn_mfma_f32_16x16x32_bf16(a, b, acc[t], 0, 0, 0);
    }
  }

  const int cb = lane & 15;
  const int rg = (lane >> 4) << 2;
  if constexpr (EPI == EPI_NONE) {
    float* Y = (float*)Yv;
#pragma unroll
    for (int t = 0; t < NTW; ++t) {
      int col = (ntb + t) * 16 + cb;
      float bv = bias[col];
#pragma unroll
      for (int r = 0; r < 4; ++r) {
        int gr = row0 + m0 + rg + r;
        Y[(size_t)gr * NOUT + col] = acc[t][r] + bv;
      }
    }
  } else if constexpr (EPI == EPI_SCALE) {
    const float* inv = (const float*)resv;
    u16* Y = (u16*)Yv;
#pragma unroll
    for (int t = 0; t < NTW; ++t) {
      int col = (ntb + t) * 16 + cb;
      float bv = bias[col];
#pragma unroll
      for (int r = 0; r < 4; ++r) {
        int gr = row0 + m0 + rg + r;
        Y[(size_t)gr * NOUT + col] = f2bf((acc[t][r] + bv) * inv[gr]);
      }
    }
  } else {  // EPI_IN
    __syncthreads();
#pragma unroll
    for (int t = 0; t < NTW; ++t) {
      int col = (ntb + t) * 16 + cb;
      float bv = bias[col];
#pragma unroll
      for (int r = 0; r < 4; ++r) sh.cs[m0 + rg + r][col] = acc[t][r] + bv;
    }
    __syncthreads();
    u32* Y = (u32*)Yv;
    for (int rr = 0; rr < 8; ++rr) {
      int r = wid * 8 + rr;
      int gr = row0 + r;
      float2 t2 = *(const float2*)&sh.cs[r][lane * 2];
      Y[(size_t)gr * 64 + lane] = pack2(fmaxf(t2.x, 0.f), fmaxf(t2.y, 0.f));
    }
  }
}

// ---------------------------------------------------------------------------
extern "C" void kernel_launch(void* const* d_in, const int* in_sizes, int n_in,
                              void* d_out, int out_size, void* d_ws, size_t ws_size,
                              hipStream_t stream) {
  (void)n_in; (void)out_size; (void)ws_size;
  const float* x      = (const float*)d_in[0];
  const int*   eidx   = (const int*)d_in[1];
  const float* degree = (const float*)d_in[2];
  const float* Win    = (const float*)d_in[3];
  const float* b_in   = (const float*)d_in[4];
  const float* W1     = (const float*)d_in[5];
  const float* b1     = (const float*)d_in[6];
  const float* W2     = (const float*)d_in[7];
  const float* b2     = (const float*)d_in[8];
  const float* ln_g   = (const float*)d_in[9];
  const float* ln_b   = (const float*)d_in[10];
  const float* out_g  = (const float*)d_in[11];
  const float* out_b  = (const float*)d_in[12];
  const float* Wout   = (const float*)d_in[13];
  const float* b_out  = (const float*)d_in[14];

  const int N = in_sizes[0] / 128;
  const int E = in_sizes[1] / 2;
  const int* esrc = eidx;
  const int* edst = eidx + E;

  char* p = (char*)d_ws;
  auto alloc = [&](size_t bytes) {
    char* q = p;
    p += (bytes + 255) & ~(size_t)255;
    return q;
  };
  float* inv    = (float*)alloc((size_t)N * 4);
  int*   offs   = (int*)alloc(((size_t)N + 1) * 4);
  int*   gcur   = (int*)alloc(256 * 4);
  int*   bsum   = (int*)alloc(1024 * 4);
  int*   col    = (int*)alloc((size_t)E * 4);
  uint2* pairs  = (uint2*)alloc((size_t)E * 8);
  u32*   h      = (u32*)alloc((size_t)N * 128 * 2);     // bf16 residual, row-major
  u32*   msc    = (u32*)alloc((size_t)N * 128 * 2);     // bf16, row-major
  u16*   pWin   = (u16*)alloc(4 * 8 * 64 * 8 * 2);
  u16*   pWout  = (u16*)alloc(4 * 4 * 64 * 8 * 2);
  u16*   pW1    = (u16*)alloc(3 * 4 * 8 * 64 * 8 * 2);
  u16*   pW2    = (u16*)alloc(3 * 4 * 8 * 64 * 8 * 2);

  pack_all_k<<<60, 256, 0, stream>>>(Win, W1, W2, Wout, pWin, pW1, pW2, pWout);

  const int nb = (N + 255) / 256;
  const int NB = (N + 511) / 512;              // dst buckets of 512 nodes
  scan_block_k<<<nb, 256, 0, stream>>>(degree, offs, bsum, N);
  scan_bsum_k<<<1, 1024, 0, stream>>>(bsum, nb);
  scan_add_k<<<(N + 256) / 256, 256, 0, stream>>>(offs, bsum, gcur, inv, degree, N, E);
  scatter_k<<<(E + 8191) / 8192, 256, 0, stream>>>(esrc, edst, gcur, pairs, E);
  fill2_k<<<NB, 256, 0, stream>>>(pairs, offs, col, N);

  const int gemmGrid = (N + 31) / 32;

  gemm_mfma<128, PREP_F32, EPI_IN><<<gemmGrid, 256, 0, stream>>>(
      x, pWin, b_in, h, nullptr, nullptr, nullptr, N);
  for (int l = 0; l < 3; ++l) {
    gemm_mfma<128, PREP_BF16, EPI_SCALE><<<gemmGrid, 256, 0, stream>>>(
        h, pW1 + (size_t)l * 16384, b1 + l * 128, msc, inv, nullptr, nullptr, N);
    spmm_gemm_k<<<gemmGrid, 256, 0, stream>>>(
        (const uint4*)msc, offs, col, inv, pW2 + (size_t)l * 16384,
        b2 + l * 128, h, ln_g + l * 128, ln_b + l * 128, N);
  }
  gemm_mfma<64, PREP_LN, EPI_NONE><<<gemmGrid, 256, 0, stream>>>(
      h, pWout, b_out, d_out, nullptr, out_g, out_b, N);
}

// Round 9
// 371.397 us; speedup vs baseline: 1.7792x; 1.0536x over previous
//
#include <hip/hip_runtime.h>
#include <cstdint>
#include <cstddef>

typedef unsigned short u16;
typedef unsigned int u32;
typedef __attribute__((ext_vector_type(2))) unsigned short u16x2;
typedef __attribute__((ext_vector_type(4))) unsigned short u16x4;
typedef __attribute__((ext_vector_type(8))) unsigned short u16x8;
typedef __attribute__((ext_vector_type(8))) __bf16 bf16x8;
typedef __attribute__((ext_vector_type(4))) float f32x4;

#define PREP_F32   0
#define PREP_BF16  1
#define PREP_LN    2
#define EPI_IN    0   // y = relu(xW + b)        -> bf16
#define EPI_SCALE 1   // y = inv[r]*(xW + b)     -> bf16
#define EPI_NONE  3   // y = xW + b              -> fp32 (NOUT=64)

__device__ __forceinline__ float wred(float v) {
#pragma unroll
  for (int m = 32; m >= 1; m >>= 1) v += __shfl_xor(v, m, 64);
  return v;
}
__device__ __forceinline__ u16 f2bf(float f) {
  u32 u = __float_as_uint(f);
  u += 0x7fffu + ((u >> 16) & 1u);
  return (u16)(u >> 16);
}
__device__ __forceinline__ float bflo(u32 u) { return __uint_as_float(u << 16); }
__device__ __forceinline__ float bfhi(u32 u) { return __uint_as_float(u & 0xffff0000u); }
__device__ __forceinline__ u32 pack2(float a, float b) {
  u32 ua = __float_as_uint(a); ua += 0x7fffu + ((ua >> 16) & 1u);
  u32 ub = __float_as_uint(b); ub += 0x7fffu + ((ub >> 16) & 1u);
  return (ua >> 16) | (ub & 0xffff0000u);
}

// ---------------- CSR build: hierarchical exclusive scan of int(degree) ----
__global__ void scan_block_k(const float* __restrict__ deg, int* __restrict__ offs,
                             int* __restrict__ bsum, int N) {
  __shared__ int sh[256];
  int tid = threadIdx.x;
  int i = blockIdx.x * 256 + tid;
  int c = (i < N) ? (int)(deg[i] + 0.5f) : 0;
  int val = c;
  for (int off = 1; off < 256; off <<= 1) {
    sh[tid] = val; __syncthreads();
    if (tid >= off) val += sh[tid - off];
    __syncthreads();
  }
  if (i < N) offs[i] = val - c;
  if (tid == 255) bsum[blockIdx.x] = val;
}

__global__ void scan_bsum_k(int* __restrict__ bsum, int nb) {
  __shared__ int sh[1024];
  int tid = threadIdx.x;
  int c = (tid < nb) ? bsum[tid] : 0;
  int val = c;
  for (int off = 1; off < 1024; off <<= 1) {
    sh[tid] = val; __syncthreads();
    if (tid >= off) val += sh[tid - off];
    __syncthreads();
  }
  if (tid < nb) bsum[tid] = val - c;
}

__global__ void scan_add_k(int* __restrict__ offs, const int* __restrict__ bsum,
                           int* __restrict__ gcur, float* __restrict__ inv,
                           const float* __restrict__ deg, int N, int E) {
  int i = blockIdx.x * 256 + threadIdx.x;
  if (i < N) {
    int o = offs[i] + bsum[i >> 8];
    offs[i] = o;
    inv[i] = rsqrtf(deg[i] + 1.0f);
    if ((i & 511) == 0) gcur[i >> 9] = o;   // bucket claim cursor = bucket base
  } else if (i == N) {
    offs[N] = E;
  }
}

// ---- phase C: bucket-scatter edges into packed u32 (src | dstoff<<17) ------
// bucket = dst>>9; dstoff = dst&511 (9 bits); src < 2^17.
__global__ __launch_bounds__(256) void scatter_k(
    const int* __restrict__ src, const int* __restrict__ dst,
    int* __restrict__ gcur, u32* __restrict__ pairs, int E) {
  __shared__ int hist[256];
  __shared__ int base_[256];
  const int tid = threadIdx.x;
  const int e0 = blockIdx.x * 8192;
  const int e1 = min(E, e0 + 8192);
  hist[tid] = 0;
  __syncthreads();
  for (int e = e0 + tid; e < e1; e += 256)
    atomicAdd(&hist[dst[e] >> 9], 1);
  __syncthreads();
  int c = hist[tid];
  if (c > 0) base_[tid] = atomicAdd(&gcur[tid], c);
  hist[tid] = 0;
  __syncthreads();
  for (int e = e0 + tid; e < e1; e += 256) {
    int d = dst[e];
    int b = d >> 9;
    int r = atomicAdd(&hist[b], 1);
    pairs[base_[b] + r] = (u32)src[e] | ((u32)(d & 511) << 17);
  }
}

// ---- phase D: per-bucket CSR fill, cursors in LDS --------------------------
__global__ __launch_bounds__(256) void fill2_k(
    const u32* __restrict__ pairs, const int* __restrict__ offs,
    int* __restrict__ col, int N) {
  __shared__ int cur[512];
  const int b = blockIdx.x;
  const int n0 = b << 9;
  const int n1 = min(N, n0 + 512);
  const int tid = threadIdx.x;
  for (int i = tid; i < n1 - n0; i += 256) cur[i] = offs[n0 + i];
  __syncthreads();
  const int e0 = offs[n0], e1 = offs[n1];
  for (int e = e0 + tid; e < e1; e += 256) {
    u32 pr = pairs[e];
    int p = atomicAdd(&cur[pr >> 17], 1);
    col[p] = (int)(pr & 0x1FFFFu);
  }
}

// ---------------- weight pre-pack, ALL matrices in one launch ---------------
__global__ void pack_all_k(const float* __restrict__ Win, const float* __restrict__ W1,
                           const float* __restrict__ W2, const float* __restrict__ Wout,
                           u16* __restrict__ pWin, u16* __restrict__ pW1,
                           u16* __restrict__ pW2, u16* __restrict__ pWout) {
  const int b = blockIdx.x;
  const float* W; u16* P; int ncol; int t;
  if (b < 8)       { W = Win;                        P = pWin;                      ncol = 128; t = b * 256 + threadIdx.x; }
  else if (b < 32) { int l = (b - 8) / 8;  W = W1 + (size_t)l * 16384;  P = pW1 + (size_t)l * 16384; ncol = 128; t = ((b - 8) % 8) * 256 + threadIdx.x; }
  else if (b < 56) { int l = (b - 32) / 8; W = W2 + (size_t)l * 16384;  P = pW2 + (size_t)l * 16384; ncol = 128; t = ((b - 32) % 8) * 256 + threadIdx.x; }
  else             { W = Wout;                       P = pWout;                     ncol = 64;  t = (b - 56) * 256 + threadIdx.x; }
  int NT = ncol >> 4;
  int total = 4 * NT * 64;
  if (t >= total) return;
  int lane = t & 63;
  int tmp = t >> 6;
  int nt = tmp % NT, kc = tmp / NT;
  int n = nt * 16 + (lane & 15);
  int kb = kc * 32 + ((lane >> 4) << 2);
  u16* dst = P + (size_t)t * 8;
#pragma unroll
  for (int j = 0; j < 8; ++j) {
    int k = kb + (j & 3) + ((j >> 2) << 4);
    dst[j] = f2bf(W[(size_t)k * ncol + n]);
  }
}

// ---------------- fused SpMM + W2 GEMM + residual/LN/ReLU -------------------
// Phase 1 (reduce-free): 16 lanes per row, 4 rows in parallel per wave,
//   2 passes of 4 rows; each lane owns a 16-B feature chunk and walks the
//   row's edge list with unroll-4 (MLP 4, full 64-B line requests).
// Phase 2: 32x128 @ 128x128 MFMA; epilogue in two 16-row halves (small LDS).
__global__ __launch_bounds__(256) void spmm_gemm_k(
    const uint4* __restrict__ msc, const int* __restrict__ offs,
    const int* __restrict__ col, const float* __restrict__ inv,
    const u16* __restrict__ Wp, const float* __restrict__ bias,
    u32* __restrict__ h, const float* __restrict__ g1,
    const float* __restrict__ lb1, int N) {
  __shared__ union {
    u16  xs[32][136];   // 8704 B  (A tile, bf16)
    float cs[16][132];  // 8448 B  (epilogue half-tile)
  } sh;
  const int tid = threadIdx.x;
  const int lane = tid & 63, wid = tid >> 6;
  const int row0 = blockIdx.x * 32;
  const int rgrp = lane >> 4, c = lane & 15;

  // ---- phase 1: aggregate rows into xs (no shuffles) ----
#pragma unroll
  for (int p = 0; p < 2; ++p) {
    const int lrow = wid * 8 + p * 4 + rgrp;
    const int d = row0 + lrow;
    const int s0 = offs[d], s1 = offs[d + 1];
    const int last = s1 - 1;
    float2 a0 = {0.f, 0.f}, a1 = {0.f, 0.f}, a2 = {0.f, 0.f}, a3 = {0.f, 0.f};
    for (int k = s0; k < s1; k += 4) {
      int sA = col[k];
      int sB = col[min(k + 1, last)];
      int sC = col[min(k + 2, last)];
      int sD = col[min(k + 3, last)];
      uint4 rA = msc[(size_t)sA * 16 + c];
      uint4 rB = msc[(size_t)sB * 16 + c];
      uint4 rC = msc[(size_t)sC * 16 + c];
      uint4 rD = msc[(size_t)sD * 16 + c];
      float mB = (k + 1 < s1) ? 1.f : 0.f;
      float mC = (k + 2 < s1) ? 1.f : 0.f;
      float mD = (k + 3 < s1) ? 1.f : 0.f;
      a0.x += bflo(rA.x); a0.y += bfhi(rA.x);
      a1.x += bflo(rA.y); a1.y += bfhi(rA.y);
      a2.x += bflo(rA.z); a2.y += bfhi(rA.z);
      a3.x += bflo(rA.w); a3.y += bfhi(rA.w);
      a0.x = fmaf(mB, bflo(rB.x), a0.x); a0.y = fmaf(mB, bfhi(rB.x), a0.y);
      a1.x = fmaf(mB, bflo(rB.y), a1.x); a1.y = fmaf(mB, bfhi(rB.y), a1.y);
      a2.x = fmaf(mB, bflo(rB.z), a2.x); a2.y = fmaf(mB, bfhi(rB.z), a2.y);
      a3.x = fmaf(mB, bflo(rB.w), a3.x); a3.y = fmaf(mB, bfhi(rB.w), a3.y);
      a0.x = fmaf(mC, bflo(rC.x), a0.x); a0.y = fmaf(mC, bfhi(rC.x), a0.y);
      a1.x = fmaf(mC, bflo(rC.y), a1.x); a1.y = fmaf(mC, bfhi(rC.y), a1.y);
      a2.x = fmaf(mC, bflo(rC.z), a2.x); a2.y = fmaf(mC, bfhi(rC.z), a2.y);
      a3.x = fmaf(mC, bflo(rC.w), a3.x); a3.y = fmaf(mC, bfhi(rC.w), a3.y);
      a0.x = fmaf(mD, bflo(rD.x), a0.x); a0.y = fmaf(mD, bfhi(rD.x), a0.y);
      a1.x = fmaf(mD, bflo(rD.y), a1.x); a1.y = fmaf(mD, bfhi(rD.y), a1.y);
      a2.x = fmaf(mD, bflo(rD.z), a2.x); a2.y = fmaf(mD, bfhi(rD.z), a2.y);
      a3.x = fmaf(mD, bflo(rD.w), a3.x); a3.y = fmaf(mD, bfhi(rD.w), a3.y);
    }
    uint4 r = msc[(size_t)d * 16 + c];   // self loop
    float iv = inv[d];
    uint4 o;
    o.x = pack2((a0.x + bflo(r.x)) * iv, (a0.y + bfhi(r.x)) * iv);
    o.y = pack2((a1.x + bflo(r.y)) * iv, (a1.y + bfhi(r.y)) * iv);
    o.z = pack2((a2.x + bflo(r.z)) * iv, (a2.y + bfhi(r.z)) * iv);
    o.w = pack2((a3.x + bflo(r.w)) * iv, (a3.y + bfhi(r.w)) * iv);
    *(uint4*)&sh.xs[lrow][c * 8] = o;
  }
  __syncthreads();

  // ---- phase 2: MFMA 32x128 @ 128x128 ----
  const int m0  = (wid >> 1) << 4;
  const int ntb = (wid & 1) << 2;
  f32x4 acc[4];
#pragma unroll
  for (int t = 0; t < 4; ++t) acc[t] = (f32x4){0.f, 0.f, 0.f, 0.f};
  const int ar  = m0 + (lane & 15);
  const int akb = (lane >> 4) << 2;
  const bf16x8* Bp = (const bf16x8*)Wp;
#pragma unroll
  for (int kc = 0; kc < 4; ++kc) {
    u16x4 lo = *(const u16x4*)&sh.xs[ar][kc * 32 + akb];
    u16x4 hi = *(const u16x4*)&sh.xs[ar][kc * 32 + akb + 16];
    u16x8 av;
#pragma unroll
    for (int j = 0; j < 4; ++j) { av[j] = lo[j]; av[j + 4] = hi[j]; }
    bf16x8 a = __builtin_bit_cast(bf16x8, av);
#pragma unroll
    for (int t = 0; t < 4; ++t) {
      bf16x8 b = Bp[(kc * 8 + ntb + t) * 64 + lane];
      acc[t] = __builtin_amdgcn_mfma_f32_16x16x32_bf16(a, b, acc[t], 0, 0, 0);
    }
  }

  // ---- epilogue: bias + residual + LN + ReLU -> h, two 16-row halves ----
  const int cb = lane & 15;
  const int rg = (lane >> 4) << 2;
  float2 gg = *(const float2*)&g1[lane * 2];
  float2 bb = *(const float2*)&lb1[lane * 2];
#pragma unroll
  for (int hh = 0; hh < 2; ++hh) {
    __syncthreads();   // xs/cs alias safe; cs half free
    if ((m0 >> 4) == hh) {
#pragma unroll
      for (int t = 0; t < 4; ++t) {
        int colm = (ntb + t) * 16 + cb;
        float bv = bias[colm];
#pragma unroll
        for (int r = 0; r < 4; ++r) sh.cs[rg + r][colm] = acc[t][r] + bv;
      }
    }
    __syncthreads();
    for (int rr = 0; rr < 4; ++rr) {
      int lr = wid * 4 + rr;                 // 0..15
      int gr = row0 + hh * 16 + lr;
      float2 t2 = *(const float2*)&sh.cs[lr][lane * 2];
      u32 hv = h[(size_t)gr * 64 + lane];
      float tx = t2.x + bflo(hv), ty = t2.y + bfhi(hv);
      float mean = wred(tx + ty) * (1.f / 128.f);
      float dx = tx - mean, dy = ty - mean;
      float var = wred(dx * dx + dy * dy) * (1.f / 128.f);
      float rstd = rsqrtf(var + 1e-5f);
      float y0 = fmaxf(dx * rstd * gg.x + bb.x, 0.f);
      float y1 = fmaxf(dy * rstd * gg.y + bb.y, 0.f);
      h[(size_t)gr * 64 + lane] = pack2(y0, y1);
    }
  }
}

// ---------------- MFMA GEMM: [N,128] @ [128,NOUT] + fused prep/epilogue ------
template <int NOUT, int PREP, int EPI>
__global__ __launch_bounds__(256) void gemm_mfma(
    const void* __restrict__ Xv, const u16* __restrict__ Wp,
    const float* __restrict__ bias, void* __restrict__ Yv,
    const void* __restrict__ resv,   // inv fp32 (SCALE)
    const float* __restrict__ g1, const float* __restrict__ lb1,
    int N) {
  constexpr int NT = NOUT / 16;
  __shared__ union {
    u16  xs[32][136];
    float cs[32][132];
  } sh;
  const int tid = threadIdx.x;
  const int lane = tid & 63, wid = tid >> 6;
  const int row0 = blockIdx.x * 32;

  if constexpr (PREP == PREP_F32) {
    const float* X = (const float*)Xv;
    for (int i = tid; i < 1024; i += 256) {
      int r = i >> 5, c4 = i & 31;
      float4 v = ((const float4*)(X + (size_t)(row0 + r) * 128))[c4];
      u16x4 o = {f2bf(v.x), f2bf(v.y), f2bf(v.z), f2bf(v.w)};
      *(u16x4*)&sh.xs[r][c4 * 4] = o;
    }
  } else if constexpr (PREP == PREP_BF16) {
    const u16x4* X = (const u16x4*)Xv;
    for (int i = tid; i < 1024; i += 256) {
      int r = i >> 5, c4 = i & 31;
      *(u16x4*)&sh.xs[r][c4 * 4] = X[(size_t)(row0 + r) * 32 + c4];
    }
  } else {  // PREP_LN: normalize bf16 rows with g1/lb1
    const u32* X = (const u32*)Xv;
    float2 gg = *(const float2*)&g1[lane * 2];
    float2 bb = *(const float2*)&lb1[lane * 2];
    for (int rr = 0; rr < 8; ++rr) {
      int r = wid * 8 + rr;
      u32 v = X[(size_t)(row0 + r) * 64 + lane];
      float tx = bflo(v), ty = bfhi(v);
      float mean = wred(tx + ty) * (1.f / 128.f);
      float dx = tx - mean, dy = ty - mean;
      float var = wred(dx * dx + dy * dy) * (1.f / 128.f);
      float rstd = rsqrtf(var + 1e-5f);
      u16x2 o = {f2bf(dx * rstd * gg.x + bb.x), f2bf(dy * rstd * gg.y + bb.y)};
      *(u16x2*)&sh.xs[r][lane * 2] = o;
    }
  }
  __syncthreads();

  constexpr int NTW = (NOUT == 128) ? 4 : 2;
  const int m0  = (NOUT == 128) ? ((wid >> 1) << 4) : ((wid & 1) << 4);
  const int ntb = (NOUT == 128) ? ((wid & 1) << 2) : ((wid >> 1) << 1);

  f32x4 acc[NTW];
#pragma unroll
  for (int t = 0; t < NTW; ++t) acc[t] = (f32x4){0.f, 0.f, 0.f, 0.f};

  const int ar  = m0 + (lane & 15);
  const int akb = (lane >> 4) << 2;
  const bf16x8* Bp = (const bf16x8*)Wp;
#pragma unroll
  for (int kc = 0; kc < 4; ++kc) {
    u16x4 lo = *(const u16x4*)&sh.xs[ar][kc * 32 + akb];
    u16x4 hi = *(const u16x4*)&sh.xs[ar][kc * 32 + akb + 16];
    u16x8 av;
#pragma unroll
    for (int j = 0; j < 4; ++j) { av[j] = lo[j]; av[j + 4] = hi[j]; }
    bf16x8 a = __builtin_bit_cast(bf16x8, av);
#pragma unroll
    for (int t = 0; t < NTW; ++t) {
      bf16x8 b = Bp[(kc * NT + ntb + t) * 64 + lane];
      acc[t] = __builtin_amdgcn_mfma_f32_16x16x32_bf16(a, b, acc[t], 0, 0, 0);
    }
  }

  const int cb = lane & 15;
  const int rg = (lane >> 4) << 2;
  if constexpr (EPI == EPI_NONE) {
    float* Y = (float*)Yv;
#pragma unroll
    for (int t = 0; t < NTW; ++t) {
      int col = (ntb + t) * 16 + cb;
      float bv = bias[col];
#pragma unroll
      for (int r = 0; r < 4; ++r) {
        int gr = row0 + m0 + rg + r;
        Y[(size_t)gr * NOUT + col] = acc[t][r] + bv;
      }
    }
  } else if constexpr (EPI == EPI_SCALE) {
    const float* inv = (const float*)resv;
    u16* Y = (u16*)Yv;
#pragma unroll
    for (int t = 0; t < NTW; ++t) {
      int col = (ntb + t) * 16 + cb;
      float bv = bias[col];
#pragma unroll
      for (int r = 0; r < 4; ++r) {
        int gr = row0 + m0 + rg + r;
        Y[(size_t)gr * NOUT + col] = f2bf((acc[t][r] + bv) * inv[gr]);
      }
    }
  } else {  // EPI_IN
    __syncthreads();
#pragma unroll
    for (int t = 0; t < NTW; ++t) {
      int col = (ntb + t) * 16 + cb;
      float bv = bias[col];
#pragma unroll
      for (int r = 0; r < 4; ++r) sh.cs[m0 + rg + r][col] = acc[t][r] + bv;
    }
    __syncthreads();
    u32* Y = (u32*)Yv;
    for (int rr = 0; rr < 8; ++rr) {
      int r = wid * 8 + rr;
      int gr = row0 + r;
      float2 t2 = *(const float2*)&sh.cs[r][lane * 2];
      Y[(size_t)gr * 64 + lane] = pack2(fmaxf(t2.x, 0.f), fmaxf(t2.y, 0.f));
    }
  }
}

// ---------------------------------------------------------------------------
extern "C" void kernel_launch(void* const* d_in, const int* in_sizes, int n_in,
                              void* d_out, int out_size, void* d_ws, size_t ws_size,
                              hipStream_t stream) {
  (void)n_in; (void)out_size; (void)ws_size;
  const float* x      = (const float*)d_in[0];
  const int*   eidx   = (const int*)d_in[1];
  const float* degree = (const float*)d_in[2];
  const float* Win    = (const float*)d_in[3];
  const float* b_in   = (const float*)d_in[4];
  const float* W1     = (const float*)d_in[5];
  const float* b1     = (const float*)d_in[6];
  const float* W2     = (const float*)d_in[7];
  const float* b2     = (const float*)d_in[8];
  const float* ln_g   = (const float*)d_in[9];
  const float* ln_b   = (const float*)d_in[10];
  const float* out_g  = (const float*)d_in[11];
  const float* out_b  = (const float*)d_in[12];
  const float* Wout   = (const float*)d_in[13];
  const float* b_out  = (const float*)d_in[14];

  const int N = in_sizes[0] / 128;
  const int E = in_sizes[1] / 2;
  const int* esrc = eidx;
  const int* edst = eidx + E;

  char* p = (char*)d_ws;
  auto alloc = [&](size_t bytes) {
    char* q = p;
    p += (bytes + 255) & ~(size_t)255;
    return q;
  };
  float* inv    = (float*)alloc((size_t)N * 4);
  int*   offs   = (int*)alloc(((size_t)N + 1) * 4);
  int*   gcur   = (int*)alloc(256 * 4);
  int*   bsum   = (int*)alloc(1024 * 4);
  int*   col    = (int*)alloc((size_t)E * 4);
  u32*   pairs  = (u32*)alloc((size_t)E * 4);
  u32*   h      = (u32*)alloc((size_t)N * 128 * 2);     // bf16 residual, row-major
  u32*   msc    = (u32*)alloc((size_t)N * 128 * 2);     // bf16, row-major
  u16*   pWin   = (u16*)alloc(4 * 8 * 64 * 8 * 2);
  u16*   pWout  = (u16*)alloc(4 * 4 * 64 * 8 * 2);
  u16*   pW1    = (u16*)alloc(3 * 4 * 8 * 64 * 8 * 2);
  u16*   pW2    = (u16*)alloc(3 * 4 * 8 * 64 * 8 * 2);

  pack_all_k<<<60, 256, 0, stream>>>(Win, W1, W2, Wout, pWin, pW1, pW2, pWout);

  const int nb = (N + 255) / 256;
  const int NB = (N + 511) / 512;              // dst buckets of 512 nodes
  scan_block_k<<<nb, 256, 0, stream>>>(degree, offs, bsum, N);
  scan_bsum_k<<<1, 1024, 0, stream>>>(bsum, nb);
  scan_add_k<<<(N + 256) / 256, 256, 0, stream>>>(offs, bsum, gcur, inv, degree, N, E);
  scatter_k<<<(E + 8191) / 8192, 256, 0, stream>>>(esrc, edst, gcur, pairs, E);
  fill2_k<<<NB, 256, 0, stream>>>(pairs, offs, col, N);

  const int gemmGrid = (N + 31) / 32;

  gemm_mfma<128, PREP_F32, EPI_IN><<<gemmGrid, 256, 0, stream>>>(
      x, pWin, b_in, h, nullptr, nullptr, nullptr, N);
  for (int l = 0; l < 3; ++l) {
    gemm_mfma<128, PREP_BF16, EPI_SCALE><<<gemmGrid, 256, 0, stream>>>(
        h, pW1 + (size_t)l * 16384, b1 + l * 128, msc, inv, nullptr, nullptr, N);
    spmm_gemm_k<<<gemmGrid, 256, 0, stream>>>(
        (const uint4*)msc, offs, col, inv, pW2 + (size_t)l * 16384,
        b2 + l * 128, h, ln_g + l * 128, ln_b + l * 128, N);
  }
  gemm_mfma<64, PREP_LN, EPI_NONE><<<gemmGrid, 256, 0, stream>>>(
      h, pWout, b_out, d_out, nullptr, out_g, out_b, N);
}

// Round 10
// 370.294 us; speedup vs baseline: 1.7845x; 1.0030x over previous
//
#include <hip/hip_runtime.h>
#include <cstdint>
#include <cstddef>

typedef unsigned short u16;
typedef unsigned int u32;
typedef __attribute__((ext_vector_type(2))) unsigned short u16x2;
typedef __attribute__((ext_vector_type(4))) unsigned short u16x4;
typedef __attribute__((ext_vector_type(8))) unsigned short u16x8;
typedef __attribute__((ext_vector_type(8))) __bf16 bf16x8;
typedef __attribute__((ext_vector_type(4))) float f32x4;

#define PREP_F32   0
#define PREP_BF16  1
#define PREP_LN    2
#define EPI_IN    0   // y = relu(xW + b)        -> bf16
#define EPI_SCALE 1   // y = inv[r]*(xW + b)     -> bf16
#define EPI_NONE  3   // y = xW + b              -> fp32 (NOUT=64)

__device__ __forceinline__ float wred(float v) {
#pragma unroll
  for (int m = 32; m >= 1; m >>= 1) v += __shfl_xor(v, m, 64);
  return v;
}
__device__ __forceinline__ u16 f2bf(float f) {
  u32 u = __float_as_uint(f);
  u += 0x7fffu + ((u >> 16) & 1u);
  return (u16)(u >> 16);
}
__device__ __forceinline__ float bflo(u32 u) { return __uint_as_float(u << 16); }
__device__ __forceinline__ float bfhi(u32 u) { return __uint_as_float(u & 0xffff0000u); }
__device__ __forceinline__ u32 pack2(float a, float b) {
  u32 ua = __float_as_uint(a); ua += 0x7fffu + ((ua >> 16) & 1u);
  u32 ub = __float_as_uint(b); ub += 0x7fffu + ((ub >> 16) & 1u);
  return (ua >> 16) | (ub & 0xffff0000u);
}

// ---------------- CSR build: hierarchical exclusive scan of int(degree) ----
__global__ void scan_block_k(const float* __restrict__ deg, int* __restrict__ offs,
                             int* __restrict__ bsum, int N) {
  __shared__ int sh[256];
  int tid = threadIdx.x;
  int i = blockIdx.x * 256 + tid;
  int c = (i < N) ? (int)(deg[i] + 0.5f) : 0;
  int val = c;
  for (int off = 1; off < 256; off <<= 1) {
    sh[tid] = val; __syncthreads();
    if (tid >= off) val += sh[tid - off];
    __syncthreads();
  }
  if (i < N) offs[i] = val - c;
  if (tid == 255) bsum[blockIdx.x] = val;
}

__global__ void scan_bsum_k(int* __restrict__ bsum, int nb) {
  __shared__ int sh[1024];
  int tid = threadIdx.x;
  int c = (tid < nb) ? bsum[tid] : 0;
  int val = c;
  for (int off = 1; off < 1024; off <<= 1) {
    sh[tid] = val; __syncthreads();
    if (tid >= off) val += sh[tid - off];
    __syncthreads();
  }
  if (tid < nb) bsum[tid] = val - c;
}

__global__ void scan_add_k(int* __restrict__ offs, const int* __restrict__ bsum,
                           int* __restrict__ gcur, float* __restrict__ inv,
                           const float* __restrict__ deg, int N, int E) {
  int i = blockIdx.x * 256 + threadIdx.x;
  if (i < N) {
    int o = offs[i] + bsum[i >> 8];
    offs[i] = o;
    inv[i] = rsqrtf(deg[i] + 1.0f);
    if ((i & 511) == 0) gcur[i >> 9] = o;   // bucket claim cursor = bucket base
  } else if (i == N) {
    offs[N] = E;
  }
}

// ---- phase C: bucket-scatter edges into packed u32 (src | dstoff<<17) ------
__global__ __launch_bounds__(256) void scatter_k(
    const int* __restrict__ src, const int* __restrict__ dst,
    int* __restrict__ gcur, u32* __restrict__ pairs, int E) {
  __shared__ int hist[256];
  __shared__ int base_[256];
  const int tid = threadIdx.x;
  const int e0 = blockIdx.x * 8192;
  const int e1 = min(E, e0 + 8192);
  hist[tid] = 0;
  __syncthreads();
  for (int e = e0 + tid; e < e1; e += 256)
    atomicAdd(&hist[dst[e] >> 9], 1);
  __syncthreads();
  int c = hist[tid];
  if (c > 0) base_[tid] = atomicAdd(&gcur[tid], c);
  hist[tid] = 0;
  __syncthreads();
  for (int e = e0 + tid; e < e1; e += 256) {
    int d = dst[e];
    int b = d >> 9;
    int r = atomicAdd(&hist[b], 1);
    pairs[base_[b] + r] = (u32)src[e] | ((u32)(d & 511) << 17);
  }
}

// ---- phase D: per-bucket CSR fill, cursors in LDS --------------------------
__global__ __launch_bounds__(256) void fill2_k(
    const u32* __restrict__ pairs, const int* __restrict__ offs,
    int* __restrict__ col, int N) {
  __shared__ int cur[512];
  const int b = blockIdx.x;
  const int n0 = b << 9;
  const int n1 = min(N, n0 + 512);
  const int tid = threadIdx.x;
  for (int i = tid; i < n1 - n0; i += 256) cur[i] = offs[n0 + i];
  __syncthreads();
  const int e0 = offs[n0], e1 = offs[n1];
  for (int e = e0 + tid; e < e1; e += 256) {
    u32 pr = pairs[e];
    int p = atomicAdd(&cur[pr >> 17], 1);
    col[p] = (int)(pr & 0x1FFFFu);
  }
}

// ---------------- weight pre-pack, ALL matrices in one launch ---------------
__global__ void pack_all_k(const float* __restrict__ Win, const float* __restrict__ W1,
                           const float* __restrict__ W2, const float* __restrict__ Wout,
                           u16* __restrict__ pWin, u16* __restrict__ pW1,
                           u16* __restrict__ pW2, u16* __restrict__ pWout) {
  const int b = blockIdx.x;
  const float* W; u16* P; int ncol; int t;
  if (b < 8)       { W = Win;                        P = pWin;                      ncol = 128; t = b * 256 + threadIdx.x; }
  else if (b < 32) { int l = (b - 8) / 8;  W = W1 + (size_t)l * 16384;  P = pW1 + (size_t)l * 16384; ncol = 128; t = ((b - 8) % 8) * 256 + threadIdx.x; }
  else if (b < 56) { int l = (b - 32) / 8; W = W2 + (size_t)l * 16384;  P = pW2 + (size_t)l * 16384; ncol = 128; t = ((b - 32) % 8) * 256 + threadIdx.x; }
  else             { W = Wout;                       P = pWout;                     ncol = 64;  t = (b - 56) * 256 + threadIdx.x; }
  int NT = ncol >> 4;
  int total = 4 * NT * 64;
  if (t >= total) return;
  int lane = t & 63;
  int tmp = t >> 6;
  int nt = tmp % NT, kc = tmp / NT;
  int n = nt * 16 + (lane & 15);
  int kb = kc * 32 + ((lane >> 4) << 2);
  u16* dst = P + (size_t)t * 8;
#pragma unroll
  for (int j = 0; j < 8; ++j) {
    int k = kb + (j & 3) + ((j >> 2) << 4);
    dst[j] = f2bf(W[(size_t)k * ncol + n]);
  }
}

// ---------------- fused SpMM + W2 GEMM + residual/LN/ReLU -------------------
// Phase 1 (reduce-free, MLP 8): 16 lanes per row, 4 rows in parallel per
//   wave, 2 passes; each lane owns a 16-B feature chunk; edge loop unroll 8.
// Phase 2: 32x128 @ 128x128 MFMA; epilogue in two 16-row halves (small LDS).
__global__ __launch_bounds__(256) void spmm_gemm_k(
    const uint4* __restrict__ msc, const int* __restrict__ offs,
    const int* __restrict__ col, const float* __restrict__ inv,
    const u16* __restrict__ Wp, const float* __restrict__ bias,
    u32* __restrict__ h, const float* __restrict__ g1,
    const float* __restrict__ lb1, int N) {
  __shared__ union {
    u16  xs[32][136];   // 8704 B  (A tile, bf16)
    float cs[16][132];  // 8448 B  (epilogue half-tile)
  } sh;
  const int tid = threadIdx.x;
  const int lane = tid & 63, wid = tid >> 6;
  const int row0 = blockIdx.x * 32;
  const int rgrp = lane >> 4, c = lane & 15;

  // ---- phase 1: aggregate rows into xs (no shuffles, MLP 8) ----
#pragma unroll
  for (int p = 0; p < 2; ++p) {
    const int lrow = wid * 8 + p * 4 + rgrp;
    const int d = row0 + lrow;
    const int s0 = offs[d], s1 = offs[d + 1];
    const int last = s1 - 1;
    float2 a0 = {0.f, 0.f}, a1 = {0.f, 0.f}, a2 = {0.f, 0.f}, a3 = {0.f, 0.f};
    for (int k = s0; k < s1; k += 8) {
      int sv[8];
#pragma unroll
      for (int j = 0; j < 8; ++j) sv[j] = col[min(k + j, last)];
      uint4 rv[8];
#pragma unroll
      for (int j = 0; j < 8; ++j) rv[j] = msc[(size_t)sv[j] * 16 + c];
#pragma unroll
      for (int j = 0; j < 8; ++j) {
        float m = (k + j < s1) ? 1.f : 0.f;
        a0.x = fmaf(m, bflo(rv[j].x), a0.x); a0.y = fmaf(m, bfhi(rv[j].x), a0.y);
        a1.x = fmaf(m, bflo(rv[j].y), a1.x); a1.y = fmaf(m, bfhi(rv[j].y), a1.y);
        a2.x = fmaf(m, bflo(rv[j].z), a2.x); a2.y = fmaf(m, bfhi(rv[j].z), a2.y);
        a3.x = fmaf(m, bflo(rv[j].w), a3.x); a3.y = fmaf(m, bfhi(rv[j].w), a3.y);
      }
    }
    uint4 r = msc[(size_t)d * 16 + c];   // self loop
    float iv = inv[d];
    uint4 o;
    o.x = pack2((a0.x + bflo(r.x)) * iv, (a0.y + bfhi(r.x)) * iv);
    o.y = pack2((a1.x + bflo(r.y)) * iv, (a1.y + bfhi(r.y)) * iv);
    o.z = pack2((a2.x + bflo(r.z)) * iv, (a2.y + bfhi(r.z)) * iv);
    o.w = pack2((a3.x + bflo(r.w)) * iv, (a3.y + bfhi(r.w)) * iv);
    *(uint4*)&sh.xs[lrow][c * 8] = o;
  }
  __syncthreads();

  // ---- phase 2: MFMA 32x128 @ 128x128 ----
  const int m0  = (wid >> 1) << 4;
  const int ntb = (wid & 1) << 2;
  f32x4 acc[4];
#pragma unroll
  for (int t = 0; t < 4; ++t) acc[t] = (f32x4){0.f, 0.f, 0.f, 0.f};
  const int ar  = m0 + (lane & 15);
  const int akb = (lane >> 4) << 2;
  const bf16x8* Bp = (const bf16x8*)Wp;
#pragma unroll
  for (int kc = 0; kc < 4; ++kc) {
    u16x4 lo = *(const u16x4*)&sh.xs[ar][kc * 32 + akb];
    u16x4 hi = *(const u16x4*)&sh.xs[ar][kc * 32 + akb + 16];
    u16x8 av;
#pragma unroll
    for (int j = 0; j < 4; ++j) { av[j] = lo[j]; av[j + 4] = hi[j]; }
    bf16x8 a = __builtin_bit_cast(bf16x8, av);
#pragma unroll
    for (int t = 0; t < 4; ++t) {
      bf16x8 b = Bp[(kc * 8 + ntb + t) * 64 + lane];
      acc[t] = __builtin_amdgcn_mfma_f32_16x16x32_bf16(a, b, acc[t], 0, 0, 0);
    }
  }

  // ---- epilogue: bias + residual + LN + ReLU -> h, two 16-row halves ----
  const int cb = lane & 15;
  const int rg = (lane >> 4) << 2;
  float2 gg = *(const float2*)&g1[lane * 2];
  float2 bb = *(const float2*)&lb1[lane * 2];
#pragma unroll
  for (int hh = 0; hh < 2; ++hh) {
    __syncthreads();   // xs/cs alias safe; cs half free
    if ((m0 >> 4) == hh) {
#pragma unroll
      for (int t = 0; t < 4; ++t) {
        int colm = (ntb + t) * 16 + cb;
        float bv = bias[colm];
#pragma unroll
        for (int r = 0; r < 4; ++r) sh.cs[rg + r][colm] = acc[t][r] + bv;
      }
    }
    __syncthreads();
    for (int rr = 0; rr < 4; ++rr) {
      int lr = wid * 4 + rr;                 // 0..15
      int gr = row0 + hh * 16 + lr;
      float2 t2 = *(const float2*)&sh.cs[lr][lane * 2];
      u32 hv = h[(size_t)gr * 64 + lane];
      float tx = t2.x + bflo(hv), ty = t2.y + bfhi(hv);
      float mean = wred(tx + ty) * (1.f / 128.f);
      float dx = tx - mean, dy = ty - mean;
      float var = wred(dx * dx + dy * dy) * (1.f / 128.f);
      float rstd = rsqrtf(var + 1e-5f);
      float y0 = fmaxf(dx * rstd * gg.x + bb.x, 0.f);
      float y1 = fmaxf(dy * rstd * gg.y + bb.y, 0.f);
      h[(size_t)gr * 64 + lane] = pack2(y0, y1);
    }
  }
}

// ---------------- MFMA GEMM: [N,128] @ [128,NOUT] + fused prep/epilogue ------
template <int NOUT, int PREP, int EPI>
__global__ __launch_bounds__(256) void gemm_mfma(
    const void* __restrict__ Xv, const u16* __restrict__ Wp,
    const float* __restrict__ bias, void* __restrict__ Yv,
    const void* __restrict__ resv,   // inv fp32 (SCALE)
    const float* __restrict__ g1, const float* __restrict__ lb1,
    int N) {
  constexpr int NT = NOUT / 16;
  __shared__ union {
    u16  xs[32][136];
    float cs[32][132];
  } sh;
  const int tid = threadIdx.x;
  const int lane = tid & 63, wid = tid >> 6;
  const int row0 = blockIdx.x * 32;

  if constexpr (PREP == PREP_F32) {
    const float* X = (const float*)Xv;
    for (int i = tid; i < 1024; i += 256) {
      int r = i >> 5, c4 = i & 31;
      float4 v = ((const float4*)(X + (size_t)(row0 + r) * 128))[c4];
      u16x4 o = {f2bf(v.x), f2bf(v.y), f2bf(v.z), f2bf(v.w)};
      *(u16x4*)&sh.xs[r][c4 * 4] = o;
    }
  } else if constexpr (PREP == PREP_BF16) {
    const u16x4* X = (const u16x4*)Xv;
    for (int i = tid; i < 1024; i += 256) {
      int r = i >> 5, c4 = i & 31;
      *(u16x4*)&sh.xs[r][c4 * 4] = X[(size_t)(row0 + r) * 32 + c4];
    }
  } else {  // PREP_LN: normalize bf16 rows with g1/lb1
    const u32* X = (const u32*)Xv;
    float2 gg = *(const float2*)&g1[lane * 2];
    float2 bb = *(const float2*)&lb1[lane * 2];
    for (int rr = 0; rr < 8; ++rr) {
      int r = wid * 8 + rr;
      u32 v = X[(size_t)(row0 + r) * 64 + lane];
      float tx = bflo(v), ty = bfhi(v);
      float mean = wred(tx + ty) * (1.f / 128.f);
      float dx = tx - mean, dy = ty - mean;
      float var = wred(dx * dx + dy * dy) * (1.f / 128.f);
      float rstd = rsqrtf(var + 1e-5f);
      u16x2 o = {f2bf(dx * rstd * gg.x + bb.x), f2bf(dy * rstd * gg.y + bb.y)};
      *(u16x2*)&sh.xs[r][lane * 2] = o;
    }
  }
  __syncthreads();

  constexpr int NTW = (NOUT == 128) ? 4 : 2;
  const int m0  = (NOUT == 128) ? ((wid >> 1) << 4) : ((wid & 1) << 4);
  const int ntb = (NOUT == 128) ? ((wid & 1) << 2) : ((wid >> 1) << 1);

  f32x4 acc[NTW];
#pragma unroll
  for (int t = 0; t < NTW; ++t) acc[t] = (f32x4){0.f, 0.f, 0.f, 0.f};

  const int ar  = m0 + (lane & 15);
  const int akb = (lane >> 4) << 2;
  const bf16x8* Bp = (const bf16x8*)Wp;
#pragma unroll
  for (int kc = 0; kc < 4; ++kc) {
    u16x4 lo = *(const u16x4*)&sh.xs[ar][kc * 32 + akb];
    u16x4 hi = *(const u16x4*)&sh.xs[ar][kc * 32 + akb + 16];
    u16x8 av;
#pragma unroll
    for (int j = 0; j < 4; ++j) { av[j] = lo[j]; av[j + 4] = hi[j]; }
    bf16x8 a = __builtin_bit_cast(bf16x8, av);
#pragma unroll
    for (int t = 0; t < NTW; ++t) {
      bf16x8 b = Bp[(kc * NT + ntb + t) * 64 + lane];
      acc[t] = __builtin_amdgcn_mfma_f32_16x16x32_bf16(a, b, acc[t], 0, 0, 0);
    }
  }

  const int cb = lane & 15;
  const int rg = (lane >> 4) << 2;
  if constexpr (EPI == EPI_NONE) {
    float* Y = (float*)Yv;
#pragma unroll
    for (int t = 0; t < NTW; ++t) {
      int col = (ntb + t) * 16 + cb;
      float bv = bias[col];
#pragma unroll
      for (int r = 0; r < 4; ++r) {
        int gr = row0 + m0 + rg + r;
        Y[(size_t)gr * NOUT + col] = acc[t][r] + bv;
      }
    }
  } else if constexpr (EPI == EPI_SCALE) {
    const float* inv = (const float*)resv;
    u16* Y = (u16*)Yv;
#pragma unroll
    for (int t = 0; t < NTW; ++t) {
      int col = (ntb + t) * 16 + cb;
      float bv = bias[col];
#pragma unroll
      for (int r = 0; r < 4; ++r) {
        int gr = row0 + m0 + rg + r;
        Y[(size_t)gr * NOUT + col] = f2bf((acc[t][r] + bv) * inv[gr]);
      }
    }
  } else {  // EPI_IN
    __syncthreads();
#pragma unroll
    for (int t = 0; t < NTW; ++t) {
      int col = (ntb + t) * 16 + cb;
      float bv = bias[col];
#pragma unroll
      for (int r = 0; r < 4; ++r) sh.cs[m0 + rg + r][col] = acc[t][r] + bv;
    }
    __syncthreads();
    u32* Y = (u32*)Yv;
    for (int rr = 0; rr < 8; ++rr) {
      int r = wid * 8 + rr;
      int gr = row0 + r;
      float2 t2 = *(const float2*)&sh.cs[r][lane * 2];
      Y[(size_t)gr * 64 + lane] = pack2(fmaxf(t2.x, 0.f), fmaxf(t2.y, 0.f));
    }
  }
}

// ---------------------------------------------------------------------------
extern "C" void kernel_launch(void* const* d_in, const int* in_sizes, int n_in,
                              void* d_out, int out_size, void* d_ws, size_t ws_size,
                              hipStream_t stream) {
  (void)n_in; (void)out_size; (void)ws_size;
  const float* x      = (const float*)d_in[0];
  const int*   eidx   = (const int*)d_in[1];
  const float* degree = (const float*)d_in[2];
  const float* Win    = (const float*)d_in[3];
  const float* b_in   = (const float*)d_in[4];
  const float* W1     = (const float*)d_in[5];
  const float* b1     = (const float*)d_in[6];
  const float* W2     = (const float*)d_in[7];
  const float* b2     = (const float*)d_in[8];
  const float* ln_g   = (const float*)d_in[9];
  const float* ln_b   = (const float*)d_in[10];
  const float* out_g  = (const float*)d_in[11];
  const float* out_b  = (const float*)d_in[12];
  const float* Wout   = (const float*)d_in[13];
  const float* b_out  = (const float*)d_in[14];

  const int N = in_sizes[0] / 128;
  const int E = in_sizes[1] / 2;
  const int* esrc = eidx;
  const int* edst = eidx + E;

  char* p = (char*)d_ws;
  auto alloc = [&](size_t bytes) {
    char* q = p;
    p += (bytes + 255) & ~(size_t)255;
    return q;
  };
  float* inv    = (float*)alloc((size_t)N * 4);
  int*   offs   = (int*)alloc(((size_t)N + 1) * 4);
  int*   gcur   = (int*)alloc(256 * 4);
  int*   bsum   = (int*)alloc(1024 * 4);
  int*   col    = (int*)alloc((size_t)E * 4);
  u32*   pairs  = (u32*)alloc((size_t)E * 4);
  u32*   h      = (u32*)alloc((size_t)N * 128 * 2);     // bf16 residual, row-major
  u32*   msc    = (u32*)alloc((size_t)N * 128 * 2);     // bf16, row-major
  u16*   pWin   = (u16*)alloc(4 * 8 * 64 * 8 * 2);
  u16*   pWout  = (u16*)alloc(4 * 4 * 64 * 8 * 2);
  u16*   pW1    = (u16*)alloc(3 * 4 * 8 * 64 * 8 * 2);
  u16*   pW2    = (u16*)alloc(3 * 4 * 8 * 64 * 8 * 2);

  pack_all_k<<<60, 256, 0, stream>>>(Win, W1, W2, Wout, pWin, pW1, pW2, pWout);

  const int nb = (N + 255) / 256;
  const int NB = (N + 511) / 512;              // dst buckets of 512 nodes
  scan_block_k<<<nb, 256, 0, stream>>>(degree, offs, bsum, N);
  scan_bsum_k<<<1, 1024, 0, stream>>>(bsum, nb);
  scan_add_k<<<(N + 256) / 256, 256, 0, stream>>>(offs, bsum, gcur, inv, degree, N, E);
  scatter_k<<<(E + 8191) / 8192, 256, 0, stream>>>(esrc, edst, gcur, pairs, E);
  fill2_k<<<NB, 256, 0, stream>>>(pairs, offs, col, N);

  const int gemmGrid = (N + 31) / 32;

  gemm_mfma<128, PREP_F32, EPI_IN><<<gemmGrid, 256, 0, stream>>>(
      x, pWin, b_in, h, nullptr, nullptr, nullptr, N);
  for (int l = 0; l < 3; ++l) {
    gemm_mfma<128, PREP_BF16, EPI_SCALE><<<gemmGrid, 256, 0, stream>>>(
        h, pW1 + (size_t)l * 16384, b1 + l * 128, msc, inv, nullptr, nullptr, N);
    spmm_gemm_k<<<gemmGrid, 256, 0, stream>>>(
        (const uint4*)msc, offs, col, inv, pW2 + (size_t)l * 16384,
        b2 + l * 128, h, ln_g + l * 128, ln_b + l * 128, N);
  }
  gemm_mfma<64, PREP_LN, EPI_NONE><<<gemmGrid, 256, 0, stream>>>(
      h, pWout, b_out, d_out, nullptr, out_g, out_b, N);
}

// Round 11
// 362.735 us; speedup vs baseline: 1.8217x; 1.0208x over previous
//
#include <hip/hip_runtime.h>
#include <cstdint>
#include <cstddef>

typedef unsigned short u16;
typedef unsigned int u32;
typedef __attribute__((ext_vector_type(2))) unsigned short u16x2;
typedef __attribute__((ext_vector_type(4))) unsigned short u16x4;
typedef __attribute__((ext_vector_type(8))) unsigned short u16x8;
typedef __attribute__((ext_vector_type(8))) __bf16 bf16x8;
typedef __attribute__((ext_vector_type(4))) float f32x4;

#define PREP_F32   0
#define PREP_BF16  1
#define PREP_LN    2
#define EPI_IN    0   // y = relu(xW + b)        -> bf16
#define EPI_SCALE 1   // y = inv[r]*(xW + b)     -> bf16
#define EPI_NONE  3   // y = xW + b              -> fp32 (NOUT=64)

__device__ __forceinline__ float wred(float v) {
#pragma unroll
  for (int m = 32; m >= 1; m >>= 1) v += __shfl_xor(v, m, 64);
  return v;
}
__device__ __forceinline__ u16 f2bf(float f) {
  u32 u = __float_as_uint(f);
  u += 0x7fffu + ((u >> 16) & 1u);
  return (u16)(u >> 16);
}
__device__ __forceinline__ float bflo(u32 u) { return __uint_as_float(u << 16); }
__device__ __forceinline__ float bfhi(u32 u) { return __uint_as_float(u & 0xffff0000u); }
__device__ __forceinline__ u32 pack2(float a, float b) {
  u32 ua = __float_as_uint(a); ua += 0x7fffu + ((ua >> 16) & 1u);
  u32 ub = __float_as_uint(b); ub += 0x7fffu + ((ub >> 16) & 1u);
  return (ua >> 16) | (ub & 0xffff0000u);
}

// ================= shared device bodies =====================================

// ---- MFMA GEMM body: [N,128] @ [128,NOUT], fused prep/epilogue -------------
template <int NOUT, int PREP, int EPI>
__device__ __forceinline__ void gemm_body(
    const void* __restrict__ Xv, const u16* __restrict__ Wp,
    const float* __restrict__ bias, void* __restrict__ Yv,
    const void* __restrict__ resv, const float* __restrict__ g1,
    const float* __restrict__ lb1, int N, int bid) {
  constexpr int NT = NOUT / 16;
  __shared__ union {
    u16  xs[32][136];
    float cs[32][132];
  } sh;
  const int tid = threadIdx.x;
  const int lane = tid & 63, wid = tid >> 6;
  const int row0 = bid * 32;

  if constexpr (PREP == PREP_F32) {
    const float* X = (const float*)Xv;
    for (int i = tid; i < 1024; i += 256) {
      int r = i >> 5, c4 = i & 31;
      float4 v = ((const float4*)(X + (size_t)(row0 + r) * 128))[c4];
      u16x4 o = {f2bf(v.x), f2bf(v.y), f2bf(v.z), f2bf(v.w)};
      *(u16x4*)&sh.xs[r][c4 * 4] = o;
    }
  } else if constexpr (PREP == PREP_BF16) {
    const u16x4* X = (const u16x4*)Xv;
    for (int i = tid; i < 1024; i += 256) {
      int r = i >> 5, c4 = i & 31;
      *(u16x4*)&sh.xs[r][c4 * 4] = X[(size_t)(row0 + r) * 32 + c4];
    }
  } else {  // PREP_LN: normalize bf16 rows with g1/lb1
    const u32* X = (const u32*)Xv;
    float2 gg = *(const float2*)&g1[lane * 2];
    float2 bb = *(const float2*)&lb1[lane * 2];
    for (int rr = 0; rr < 8; ++rr) {
      int r = wid * 8 + rr;
      u32 v = X[(size_t)(row0 + r) * 64 + lane];
      float tx = bflo(v), ty = bfhi(v);
      float mean = wred(tx + ty) * (1.f / 128.f);
      float dx = tx - mean, dy = ty - mean;
      float var = wred(dx * dx + dy * dy) * (1.f / 128.f);
      float rstd = rsqrtf(var + 1e-5f);
      u16x2 o = {f2bf(dx * rstd * gg.x + bb.x), f2bf(dy * rstd * gg.y + bb.y)};
      *(u16x2*)&sh.xs[r][lane * 2] = o;
    }
  }
  __syncthreads();

  constexpr int NTW = (NOUT == 128) ? 4 : 2;
  const int m0  = (NOUT == 128) ? ((wid >> 1) << 4) : ((wid & 1) << 4);
  const int ntb = (NOUT == 128) ? ((wid & 1) << 2) : ((wid >> 1) << 1);

  f32x4 acc[NTW];
#pragma unroll
  for (int t = 0; t < NTW; ++t) acc[t] = (f32x4){0.f, 0.f, 0.f, 0.f};

  const int ar  = m0 + (lane & 15);
  const int akb = (lane >> 4) << 2;
  const bf16x8* Bp = (const bf16x8*)Wp;
#pragma unroll
  for (int kc = 0; kc < 4; ++kc) {
    u16x4 lo = *(const u16x4*)&sh.xs[ar][kc * 32 + akb];
    u16x4 hi = *(const u16x4*)&sh.xs[ar][kc * 32 + akb + 16];
    u16x8 av;
#pragma unroll
    for (int j = 0; j < 4; ++j) { av[j] = lo[j]; av[j + 4] = hi[j]; }
    bf16x8 a = __builtin_bit_cast(bf16x8, av);
#pragma unroll
    for (int t = 0; t < NTW; ++t) {
      bf16x8 b = Bp[(kc * NT + ntb + t) * 64 + lane];
      acc[t] = __builtin_amdgcn_mfma_f32_16x16x32_bf16(a, b, acc[t], 0, 0, 0);
    }
  }

  const int cb = lane & 15;
  const int rg = (lane >> 4) << 2;
  if constexpr (EPI == EPI_NONE) {
    float* Y = (float*)Yv;
#pragma unroll
    for (int t = 0; t < NTW; ++t) {
      int col = (ntb + t) * 16 + cb;
      float bv = bias[col];
#pragma unroll
      for (int r = 0; r < 4; ++r) {
        int gr = row0 + m0 + rg + r;
        Y[(size_t)gr * NOUT + col] = acc[t][r] + bv;
      }
    }
  } else if constexpr (EPI == EPI_SCALE) {
    const float* inv = (const float*)resv;
    u16* Y = (u16*)Yv;
#pragma unroll
    for (int t = 0; t < NTW; ++t) {
      int col = (ntb + t) * 16 + cb;
      float bv = bias[col];
#pragma unroll
      for (int r = 0; r < 4; ++r) {
        int gr = row0 + m0 + rg + r;
        Y[(size_t)gr * NOUT + col] = f2bf((acc[t][r] + bv) * inv[gr]);
      }
    }
  } else {  // EPI_IN
    __syncthreads();
#pragma unroll
    for (int t = 0; t < NTW; ++t) {
      int col = (ntb + t) * 16 + cb;
      float bv = bias[col];
#pragma unroll
      for (int r = 0; r < 4; ++r) sh.cs[m0 + rg + r][col] = acc[t][r] + bv;
    }
    __syncthreads();
    u32* Y = (u32*)Yv;
    for (int rr = 0; rr < 8; ++rr) {
      int r = wid * 8 + rr;
      int gr = row0 + r;
      float2 t2 = *(const float2*)&sh.cs[r][lane * 2];
      Y[(size_t)gr * 64 + lane] = pack2(fmaxf(t2.x, 0.f), fmaxf(t2.y, 0.f));
    }
  }
}

// ================= merged dispatches ========================================

// D1: blocks [0,nb): scan_block over degree (+ inv compute); [nb,nb+60): pack_w
__global__ __launch_bounds__(256) void d1_scan_pack_k(
    const float* __restrict__ deg, int* __restrict__ offs,
    int* __restrict__ bsum, float* __restrict__ inv, int N, int nb,
    const float* __restrict__ Win, const float* __restrict__ W1,
    const float* __restrict__ W2, const float* __restrict__ Wout,
    u16* __restrict__ pWin, u16* __restrict__ pW1,
    u16* __restrict__ pW2, u16* __restrict__ pWout) {
  if ((int)blockIdx.x < nb) {
    __shared__ int sh[256];
    int tid = threadIdx.x;
    int i = blockIdx.x * 256 + tid;
    int c = (i < N) ? (int)(deg[i] + 0.5f) : 0;
    if (i < N) inv[i] = rsqrtf(deg[i] + 1.0f);
    int val = c;
    for (int off = 1; off < 256; off <<= 1) {
      sh[tid] = val; __syncthreads();
      if (tid >= off) val += sh[tid - off];
      __syncthreads();
    }
    if (i < N) offs[i] = val - c;
    if (tid == 255) bsum[blockIdx.x] = val;
    return;
  }
  // pack: sub-block b in [0,60)
  const int b = blockIdx.x - nb;
  const float* W; u16* P; int ncol; int t;
  if (b < 8)       { W = Win;                        P = pWin;                      ncol = 128; t = b * 256 + threadIdx.x; }
  else if (b < 32) { int l = (b - 8) / 8;  W = W1 + (size_t)l * 16384;  P = pW1 + (size_t)l * 16384; ncol = 128; t = ((b - 8) % 8) * 256 + threadIdx.x; }
  else if (b < 56) { int l = (b - 32) / 8; W = W2 + (size_t)l * 16384;  P = pW2 + (size_t)l * 16384; ncol = 128; t = ((b - 32) % 8) * 256 + threadIdx.x; }
  else             { W = Wout;                       P = pWout;                     ncol = 64;  t = (b - 56) * 256 + threadIdx.x; }
  int NT = ncol >> 4;
  int total = 4 * NT * 64;
  if (t >= total) return;
  int lane = t & 63;
  int tmp = t >> 6;
  int nt = tmp % NT, kc = tmp / NT;
  int n = nt * 16 + (lane & 15);
  int kb = kc * 32 + ((lane >> 4) << 2);
  u16* dst = P + (size_t)t * 8;
#pragma unroll
  for (int j = 0; j < 8; ++j) {
    int k = kb + (j & 3) + ((j >> 2) << 4);
    dst[j] = f2bf(W[(size_t)k * ncol + n]);
  }
}

// D2: blocks [0,gemmGrid): EPI_IN GEMM; last block: exclusive-scan bsum (nb<=512)
__global__ __launch_bounds__(256) void d2_gemmin_bsum_k(
    const void* __restrict__ Xv, const u16* __restrict__ Wp,
    const float* __restrict__ bias, void* __restrict__ Yv, int N,
    int* __restrict__ bsum, int nb) {
  if (blockIdx.x == gridDim.x - 1) {
    __shared__ int a[512], b[512];
    int tid = threadIdx.x;
    for (int i = tid; i < 512; i += 256) a[i] = (i < nb) ? bsum[i] : 0;
    __syncthreads();
    int* src = a; int* dst = b;
    for (int off = 1; off < 512; off <<= 1) {
      for (int i = tid; i < 512; i += 256)
        dst[i] = (i >= off) ? src[i] + src[i - off] : src[i];
      __syncthreads();
      int* t = src; src = dst; dst = t;
    }
    for (int i = tid; i < nb; i += 256) bsum[i] = (i > 0) ? src[i - 1] : 0;
    return;
  }
  gemm_body<128, PREP_F32, EPI_IN>(Xv, Wp, bias, Yv, nullptr, nullptr, nullptr,
                                   N, blockIdx.x);
}

// D3: blocks [0,gemmGrid): EPI_SCALE GEMM (layer 0); rest: scan_add (offs/gcur)
__global__ __launch_bounds__(256) void d3_gemmscale_scanadd_k(
    const void* __restrict__ Xv, const u16* __restrict__ Wp,
    const float* __restrict__ bias, void* __restrict__ Yv,
    const float* __restrict__ inv, int N,
    int* __restrict__ offs, const int* __restrict__ bsum,
    int* __restrict__ gcur, int E, int gemmGrid) {
  if ((int)blockIdx.x >= gemmGrid) {
    int i = (blockIdx.x - gemmGrid) * 256 + threadIdx.x;
    if (i < N) {
      int o = offs[i] + bsum[i >> 8];
      offs[i] = o;
      if ((i & 511) == 0) gcur[i >> 9] = o;
    } else if (i == N) {
      offs[N] = E;
    }
    return;
  }
  gemm_body<128, PREP_BF16, EPI_SCALE>(Xv, Wp, bias, Yv, inv, nullptr, nullptr,
                                       N, blockIdx.x);
}

// plain GEMM wrapper (SCALE layers 1-2, final LN+GEMM)
template <int NOUT, int PREP, int EPI>
__global__ __launch_bounds__(256) void gemm_mfma(
    const void* __restrict__ Xv, const u16* __restrict__ Wp,
    const float* __restrict__ bias, void* __restrict__ Yv,
    const void* __restrict__ resv, const float* __restrict__ g1,
    const float* __restrict__ lb1, int N) {
  gemm_body<NOUT, PREP, EPI>(Xv, Wp, bias, Yv, resv, g1, lb1, N, blockIdx.x);
}

// ---- phase C: bucket-scatter edges into packed u32 (src | dstoff<<17) ------
__global__ __launch_bounds__(256) void scatter_k(
    const int* __restrict__ src, const int* __restrict__ dst,
    int* __restrict__ gcur, u32* __restrict__ pairs, int E) {
  __shared__ int hist[256];
  __shared__ int base_[256];
  const int tid = threadIdx.x;
  const int e0 = blockIdx.x * 8192;
  const int e1 = min(E, e0 + 8192);
  hist[tid] = 0;
  __syncthreads();
  for (int e = e0 + tid; e < e1; e += 256)
    atomicAdd(&hist[dst[e] >> 9], 1);
  __syncthreads();
  int c = hist[tid];
  if (c > 0) base_[tid] = atomicAdd(&gcur[tid], c);
  hist[tid] = 0;
  __syncthreads();
  for (int e = e0 + tid; e < e1; e += 256) {
    int d = dst[e];
    int b = d >> 9;
    int r = atomicAdd(&hist[b], 1);
    pairs[base_[b] + r] = (u32)src[e] | ((u32)(d & 511) << 17);
  }
}

// ---- phase D: per-bucket CSR fill, cursors in LDS --------------------------
__global__ __launch_bounds__(256) void fill2_k(
    const u32* __restrict__ pairs, const int* __restrict__ offs,
    int* __restrict__ col, int N) {
  __shared__ int cur[512];
  const int b = blockIdx.x;
  const int n0 = b << 9;
  const int n1 = min(N, n0 + 512);
  const int tid = threadIdx.x;
  for (int i = tid; i < n1 - n0; i += 256) cur[i] = offs[n0 + i];
  __syncthreads();
  const int e0 = offs[n0], e1 = offs[n1];
  for (int e = e0 + tid; e < e1; e += 256) {
    u32 pr = pairs[e];
    int p = atomicAdd(&cur[pr >> 17], 1);
    col[p] = (int)(pr & 0x1FFFFu);
  }
}

// ---------------- fused SpMM + W2 GEMM + residual/LN/ReLU -------------------
__global__ __launch_bounds__(256) void spmm_gemm_k(
    const uint4* __restrict__ msc, const int* __restrict__ offs,
    const int* __restrict__ col, const float* __restrict__ inv,
    const u16* __restrict__ Wp, const float* __restrict__ bias,
    u32* __restrict__ h, const float* __restrict__ g1,
    const float* __restrict__ lb1, int N) {
  __shared__ union {
    u16  xs[32][136];   // 8704 B  (A tile, bf16)
    float cs[16][132];  // 8448 B  (epilogue half-tile)
  } sh;
  const int tid = threadIdx.x;
  const int lane = tid & 63, wid = tid >> 6;
  const int row0 = blockIdx.x * 32;
  const int rgrp = lane >> 4, c = lane & 15;

  // ---- phase 1: aggregate rows into xs (no shuffles, MLP 8) ----
#pragma unroll
  for (int p = 0; p < 2; ++p) {
    const int lrow = wid * 8 + p * 4 + rgrp;
    const int d = row0 + lrow;
    const int s0 = offs[d], s1 = offs[d + 1];
    const int last = s1 - 1;
    float2 a0 = {0.f, 0.f}, a1 = {0.f, 0.f}, a2 = {0.f, 0.f}, a3 = {0.f, 0.f};
    for (int k = s0; k < s1; k += 8) {
      int sv[8];
#pragma unroll
      for (int j = 0; j < 8; ++j) sv[j] = col[min(k + j, last)];
      uint4 rv[8];
#pragma unroll
      for (int j = 0; j < 8; ++j) rv[j] = msc[(size_t)sv[j] * 16 + c];
#pragma unroll
      for (int j = 0; j < 8; ++j) {
        float m = (k + j < s1) ? 1.f : 0.f;
        a0.x = fmaf(m, bflo(rv[j].x), a0.x); a0.y = fmaf(m, bfhi(rv[j].x), a0.y);
        a1.x = fmaf(m, bflo(rv[j].y), a1.x); a1.y = fmaf(m, bfhi(rv[j].y), a1.y);
        a2.x = fmaf(m, bflo(rv[j].z), a2.x); a2.y = fmaf(m, bfhi(rv[j].z), a2.y);
        a3.x = fmaf(m, bflo(rv[j].w), a3.x); a3.y = fmaf(m, bfhi(rv[j].w), a3.y);
      }
    }
    uint4 r = msc[(size_t)d * 16 + c];   // self loop
    float iv = inv[d];
    uint4 o;
    o.x = pack2((a0.x + bflo(r.x)) * iv, (a0.y + bfhi(r.x)) * iv);
    o.y = pack2((a1.x + bflo(r.y)) * iv, (a1.y + bfhi(r.y)) * iv);
    o.z = pack2((a2.x + bflo(r.z)) * iv, (a2.y + bfhi(r.z)) * iv);
    o.w = pack2((a3.x + bflo(r.w)) * iv, (a3.y + bfhi(r.w)) * iv);
    *(uint4*)&sh.xs[lrow][c * 8] = o;
  }
  __syncthreads();

  // ---- phase 2: MFMA 32x128 @ 128x128 ----
  const int m0  = (wid >> 1) << 4;
  const int ntb = (wid & 1) << 2;
  f32x4 acc[4];
#pragma unroll
  for (int t = 0; t < 4; ++t) acc[t] = (f32x4){0.f, 0.f, 0.f, 0.f};
  const int ar  = m0 + (lane & 15);
  const int akb = (lane >> 4) << 2;
  const bf16x8* Bp = (const bf16x8*)Wp;
#pragma unroll
  for (int kc = 0; kc < 4; ++kc) {
    u16x4 lo = *(const u16x4*)&sh.xs[ar][kc * 32 + akb];
    u16x4 hi = *(const u16x4*)&sh.xs[ar][kc * 32 + akb + 16];
    u16x8 av;
#pragma unroll
    for (int j = 0; j < 4; ++j) { av[j] = lo[j]; av[j + 4] = hi[j]; }
    bf16x8 a = __builtin_bit_cast(bf16x8, av);
#pragma unroll
    for (int t = 0; t < 4; ++t) {
      bf16x8 b = Bp[(kc * 8 + ntb + t) * 64 + lane];
      acc[t] = __builtin_amdgcn_mfma_f32_16x16x32_bf16(a, b, acc[t], 0, 0, 0);
    }
  }

  // ---- epilogue: bias + residual + LN + ReLU -> h, two 16-row halves ----
  const int cb = lane & 15;
  const int rg = (lane >> 4) << 2;
  float2 gg = *(const float2*)&g1[lane * 2];
  float2 bb = *(const float2*)&lb1[lane * 2];
#pragma unroll
  for (int hh = 0; hh < 2; ++hh) {
    __syncthreads();
    if ((m0 >> 4) == hh) {
#pragma unroll
      for (int t = 0; t < 4; ++t) {
        int colm = (ntb + t) * 16 + cb;
        float bv = bias[colm];
#pragma unroll
        for (int r = 0; r < 4; ++r) sh.cs[rg + r][colm] = acc[t][r] + bv;
      }
    }
    __syncthreads();
    for (int rr = 0; rr < 4; ++rr) {
      int lr = wid * 4 + rr;                 // 0..15
      int gr = row0 + hh * 16 + lr;
      float2 t2 = *(const float2*)&sh.cs[lr][lane * 2];
      u32 hv = h[(size_t)gr * 64 + lane];
      float tx = t2.x + bflo(hv), ty = t2.y + bfhi(hv);
      float mean = wred(tx + ty) * (1.f / 128.f);
      float dx = tx - mean, dy = ty - mean;
      float var = wred(dx * dx + dy * dy) * (1.f / 128.f);
      float rstd = rsqrtf(var + 1e-5f);
      float y0 = fmaxf(dx * rstd * gg.x + bb.x, 0.f);
      float y1 = fmaxf(dy * rstd * gg.y + bb.y, 0.f);
      h[(size_t)gr * 64 + lane] = pack2(y0, y1);
    }
  }
}

// ---------------------------------------------------------------------------
extern "C" void kernel_launch(void* const* d_in, const int* in_sizes, int n_in,
                              void* d_out, int out_size, void* d_ws, size_t ws_size,
                              hipStream_t stream) {
  (void)n_in; (void)out_size; (void)ws_size;
  const float* x      = (const float*)d_in[0];
  const int*   eidx   = (const int*)d_in[1];
  const float* degree = (const float*)d_in[2];
  const float* Win    = (const float*)d_in[3];
  const float* b_in   = (const float*)d_in[4];
  const float* W1     = (const float*)d_in[5];
  const float* b1     = (const float*)d_in[6];
  const float* W2     = (const float*)d_in[7];
  const float* b2     = (const float*)d_in[8];
  const float* ln_g   = (const float*)d_in[9];
  const float* ln_b   = (const float*)d_in[10];
  const float* out_g  = (const float*)d_in[11];
  const float* out_b  = (const float*)d_in[12];
  const float* Wout   = (const float*)d_in[13];
  const float* b_out  = (const float*)d_in[14];

  const int N = in_sizes[0] / 128;
  const int E = in_sizes[1] / 2;
  const int* esrc = eidx;
  const int* edst = eidx + E;

  char* p = (char*)d_ws;
  auto alloc = [&](size_t bytes) {
    char* q = p;
    p += (bytes + 255) & ~(size_t)255;
    return q;
  };
  float* inv    = (float*)alloc((size_t)N * 4);
  int*   offs   = (int*)alloc(((size_t)N + 1) * 4);
  int*   gcur   = (int*)alloc(256 * 4);
  int*   bsum   = (int*)alloc(1024 * 4);
  int*   col    = (int*)alloc((size_t)E * 4);
  u32*   pairs  = (u32*)alloc((size_t)E * 4);
  u32*   h      = (u32*)alloc((size_t)N * 128 * 2);     // bf16 residual, row-major
  u32*   msc    = (u32*)alloc((size_t)N * 128 * 2);     // bf16, row-major
  u16*   pWin   = (u16*)alloc(4 * 8 * 64 * 8 * 2);
  u16*   pWout  = (u16*)alloc(4 * 4 * 64 * 8 * 2);
  u16*   pW1    = (u16*)alloc(3 * 4 * 8 * 64 * 8 * 2);
  u16*   pW2    = (u16*)alloc(3 * 4 * 8 * 64 * 8 * 2);

  const int nb = (N + 255) / 256;              // 391 scan blocks (<=512 req'd)
  const int NB = (N + 511) / 512;              // 196 dst buckets
  const int gemmGrid = (N + 31) / 32;          // 3125
  const int saGrid = (N + 256) / 256;          // 392 scan_add blocks

  // D1: degree scan (block-local) + inv + weight packing
  d1_scan_pack_k<<<nb + 60, 256, 0, stream>>>(
      degree, offs, bsum, inv, N, nb,
      Win, W1, W2, Wout, pWin, pW1, pW2, pWout);
  // D2: input GEMM (x -> h) + bsum exclusive scan
  d2_gemmin_bsum_k<<<gemmGrid + 1, 256, 0, stream>>>(
      x, pWin, b_in, h, N, bsum, nb);
  // D3: layer-0 W1 GEMM (h -> msc) + offs/gcur finalize
  d3_gemmscale_scanadd_k<<<gemmGrid + saGrid, 256, 0, stream>>>(
      h, pW1, b1, msc, inv, N, offs, bsum, gcur, E, gemmGrid);
  // D4/D5: edge bucket-scatter, CSR fill
  scatter_k<<<(E + 8191) / 8192, 256, 0, stream>>>(esrc, edst, gcur, pairs, E);
  fill2_k<<<NB, 256, 0, stream>>>(pairs, offs, col, N);

  // layer 0 sparse+W2
  spmm_gemm_k<<<gemmGrid, 256, 0, stream>>>(
      (const uint4*)msc, offs, col, inv, pW2, b2, h, ln_g, ln_b, N);
  // layers 1..2
  for (int l = 1; l < 3; ++l) {
    gemm_mfma<128, PREP_BF16, EPI_SCALE><<<gemmGrid, 256, 0, stream>>>(
        h, pW1 + (size_t)l * 16384, b1 + l * 128, msc, inv, nullptr, nullptr, N);
    spmm_gemm_k<<<gemmGrid, 256, 0, stream>>>(
        (const uint4*)msc, offs, col, inv, pW2 + (size_t)l * 16384,
        b2 + l * 128, h, ln_g + l * 128, ln_b + l * 128, N);
  }
  gemm_mfma<64, PREP_LN, EPI_NONE><<<gemmGrid, 256, 0, stream>>>(
      h, pWout, b_out, d_out, nullptr, out_g, out_b, N);
}

// Round 12
// 333.857 us; speedup vs baseline: 1.9793x; 1.0865x over previous
//
#include <hip/hip_runtime.h>
#include <cstdint>
#include <cstddef>

typedef unsigned short u16;
typedef unsigned int u32;
typedef __attribute__((ext_vector_type(2))) unsigned short u16x2;
typedef __attribute__((ext_vector_type(4))) unsigned short u16x4;
typedef __attribute__((ext_vector_type(8))) unsigned short u16x8;
typedef __attribute__((ext_vector_type(8))) __bf16 bf16x8;
typedef __attribute__((ext_vector_type(4))) float f32x4;

__device__ __forceinline__ float wred(float v) {
#pragma unroll
  for (int m = 32; m >= 1; m >>= 1) v += __shfl_xor(v, m, 64);
  return v;
}
__device__ __forceinline__ u16 f2bf(float f) {
  u32 u = __float_as_uint(f);
  u += 0x7fffu + ((u >> 16) & 1u);
  return (u16)(u >> 16);
}
__device__ __forceinline__ float bflo(u32 u) { return __uint_as_float(u << 16); }
__device__ __forceinline__ float bfhi(u32 u) { return __uint_as_float(u & 0xffff0000u); }
__device__ __forceinline__ u32 pack2(float a, float b) {
  u32 ua = __float_as_uint(a); ua += 0x7fffu + ((ua >> 16) & 1u);
  u32 ub = __float_as_uint(b); ub += 0x7fffu + ((ub >> 16) & 1u);
  return (ua >> 16) | (ub & 0xffff0000u);
}

// 32x128 @ 128x128 MFMA from xs tile (uses m0, ntb, lane, xs from scope)
#define MFMA128_FROM_XS(ACC, BP)                                               \
  {                                                                            \
    const int ar_ = m0 + (lane & 15);                                          \
    const int akb_ = (lane >> 4) << 2;                                         \
    _Pragma("unroll")                                                          \
    for (int kc = 0; kc < 4; ++kc) {                                           \
      u16x4 lo = *(const u16x4*)&xs[ar_][kc * 32 + akb_];                      \
      u16x4 hi = *(const u16x4*)&xs[ar_][kc * 32 + akb_ + 16];                 \
      u16x8 av;                                                                \
      _Pragma("unroll")                                                        \
      for (int j = 0; j < 4; ++j) { av[j] = lo[j]; av[j + 4] = hi[j]; }        \
      bf16x8 a = __builtin_bit_cast(bf16x8, av);                               \
      _Pragma("unroll")                                                        \
      for (int t = 0; t < 4; ++t) {                                            \
        bf16x8 b = (BP)[(kc * 8 + ntb + t) * 64 + lane];                       \
        (ACC)[t] = __builtin_amdgcn_mfma_f32_16x16x32_bf16(a, b, (ACC)[t], 0, 0, 0); \
      }                                                                        \
    }                                                                          \
  }

// D1: blocks [0,nb): scan_block over degree (+ inv); [nb,nb+60): weight pack
__global__ __launch_bounds__(256) void d1_scan_pack_k(
    const float* __restrict__ deg, int* __restrict__ offs,
    int* __restrict__ bsum, float* __restrict__ inv, int N, int nb,
    const float* __restrict__ Win, const float* __restrict__ W1,
    const float* __restrict__ W2, const float* __restrict__ Wout,
    u16* __restrict__ pWin, u16* __restrict__ pW1,
    u16* __restrict__ pW2, u16* __restrict__ pWout) {
  if ((int)blockIdx.x < nb) {
    __shared__ int sh[256];
    int tid = threadIdx.x;
    int i = blockIdx.x * 256 + tid;
    int c = (i < N) ? (int)(deg[i] + 0.5f) : 0;
    if (i < N) inv[i] = rsqrtf(deg[i] + 1.0f);
    int val = c;
    for (int off = 1; off < 256; off <<= 1) {
      sh[tid] = val; __syncthreads();
      if (tid >= off) val += sh[tid - off];
      __syncthreads();
    }
    if (i < N) offs[i] = val - c;
    if (tid == 255) bsum[blockIdx.x] = val;
    return;
  }
  const int b = blockIdx.x - nb;
  const float* W; u16* P; int ncol; int t;
  if (b < 8)       { W = Win;                        P = pWin;                      ncol = 128; t = b * 256 + threadIdx.x; }
  else if (b < 32) { int l = (b - 8) / 8;  W = W1 + (size_t)l * 16384;  P = pW1 + (size_t)l * 16384; ncol = 128; t = ((b - 8) % 8) * 256 + threadIdx.x; }
  else if (b < 56) { int l = (b - 32) / 8; W = W2 + (size_t)l * 16384;  P = pW2 + (size_t)l * 16384; ncol = 128; t = ((b - 32) % 8) * 256 + threadIdx.x; }
  else             { W = Wout;                       P = pWout;                     ncol = 64;  t = (b - 56) * 256 + threadIdx.x; }
  int NT = ncol >> 4;
  int total = 4 * NT * 64;
  if (t >= total) return;
  int lane = t & 63;
  int tmp = t >> 6;
  int nt = tmp % NT, kc = tmp / NT;
  int n = nt * 16 + (lane & 15);
  int kb = kc * 32 + ((lane >> 4) << 2);
  u16* dst = P + (size_t)t * 8;
#pragma unroll
  for (int j = 0; j < 8; ++j) {
    int k = kb + (j & 3) + ((j >> 2) << 4);
    dst[j] = f2bf(W[(size_t)k * ncol + n]);
  }
}

// D2: blocks [0,gemmGrid): fused x@Win+ReLU -> h, then y@W1 -> msc
//     last block: exclusive-scan of bsum (nb <= 512)
__global__ __launch_bounds__(256) void in_scale_k(
    const float* __restrict__ x, const u16* __restrict__ pWin,
    const float* __restrict__ b_in, const u16* __restrict__ pW1,
    const float* __restrict__ b1, const float* __restrict__ inv,
    u32* __restrict__ h, u16* __restrict__ msc, int N,
    int* __restrict__ bsum, int nb) {
  if (blockIdx.x == gridDim.x - 1) {
    __shared__ int a_[512], b_[512];
    int tid = threadIdx.x;
    for (int i = tid; i < 512; i += 256) a_[i] = (i < nb) ? bsum[i] : 0;
    __syncthreads();
    int* src = a_; int* dst = b_;
    for (int off = 1; off < 512; off <<= 1) {
      for (int i = tid; i < 512; i += 256)
        dst[i] = (i >= off) ? src[i] + src[i - off] : src[i];
      __syncthreads();
      int* t = src; src = dst; dst = t;
    }
    for (int i = tid; i < nb; i += 256) bsum[i] = (i > 0) ? src[i - 1] : 0;
    return;
  }
  __shared__ u16 xs[32][136];
  __shared__ float cs[16][132];
  const int tid = threadIdx.x;
  const int lane = tid & 63, wid = tid >> 6;
  const int row0 = blockIdx.x * 32;

  // stage x (fp32 -> bf16)
  for (int i = tid; i < 1024; i += 256) {
    int r = i >> 5, c4 = i & 31;
    float4 v = ((const float4*)(x + (size_t)(row0 + r) * 128))[c4];
    u16x4 o = {f2bf(v.x), f2bf(v.y), f2bf(v.z), f2bf(v.w)};
    *(u16x4*)&xs[r][c4 * 4] = o;
  }
  __syncthreads();

  const int m0  = (wid >> 1) << 4;
  const int ntb = (wid & 1) << 2;
  f32x4 acc[4];
#pragma unroll
  for (int t = 0; t < 4; ++t) acc[t] = (f32x4){0.f, 0.f, 0.f, 0.f};
  MFMA128_FROM_XS(acc, (const bf16x8*)pWin);

  const int cb = lane & 15;
  const int rg = (lane >> 4) << 2;
#pragma unroll
  for (int hh = 0; hh < 2; ++hh) {
    __syncthreads();
    if ((m0 >> 4) == hh) {
#pragma unroll
      for (int t = 0; t < 4; ++t) {
        int colm = (ntb + t) * 16 + cb;
        float bv = b_in[colm];
#pragma unroll
        for (int r = 0; r < 4; ++r) cs[rg + r][colm] = acc[t][r] + bv;
      }
    }
    __syncthreads();
    for (int rr = 0; rr < 4; ++rr) {
      int lr = wid * 4 + rr;
      int r = hh * 16 + lr;
      int gr = row0 + r;
      float2 t2 = *(const float2*)&cs[lr][lane * 2];
      u32 pk = pack2(fmaxf(t2.x, 0.f), fmaxf(t2.y, 0.f));
      h[(size_t)gr * 64 + lane] = pk;
      *(u32*)&xs[r][lane * 2] = pk;
    }
  }
  __syncthreads();

  // phase 3: y @ W1 -> msc (scaled by inv)
  f32x4 acc2[4];
#pragma unroll
  for (int t = 0; t < 4; ++t) acc2[t] = (f32x4){0.f, 0.f, 0.f, 0.f};
  MFMA128_FROM_XS(acc2, (const bf16x8*)pW1);
  float iv4[4];
#pragma unroll
  for (int r = 0; r < 4; ++r) iv4[r] = inv[row0 + m0 + rg + r];
#pragma unroll
  for (int t = 0; t < 4; ++t) {
    int colm = (ntb + t) * 16 + cb;
    float bv = b1[colm];
#pragma unroll
    for (int r = 0; r < 4; ++r) {
      int gr = row0 + m0 + rg + r;
      msc[(size_t)gr * 128 + colm] = f2bf((acc2[t][r] + bv) * iv4[r]);
    }
  }
}

// D3: finalize offs (+ bucket cursors)
__global__ void scan_add_k(int* __restrict__ offs, const int* __restrict__ bsum,
                           int* __restrict__ gcur, int N, int E) {
  int i = blockIdx.x * 256 + threadIdx.x;
  if (i < N) {
    int o = offs[i] + bsum[i >> 8];
    offs[i] = o;
    if ((i & 511) == 0) gcur[i >> 9] = o;
  } else if (i == N) {
    offs[N] = E;
  }
}

// D4: bucket-scatter edges into packed u32 (src | dstoff<<17)
__global__ __launch_bounds__(256) void scatter_k(
    const int* __restrict__ src, const int* __restrict__ dst,
    int* __restrict__ gcur, u32* __restrict__ pairs, int E) {
  __shared__ int hist[256];
  __shared__ int base_[256];
  const int tid = threadIdx.x;
  const int e0 = blockIdx.x * 8192;
  const int e1 = min(E, e0 + 8192);
  hist[tid] = 0;
  __syncthreads();
  for (int e = e0 + tid; e < e1; e += 256)
    atomicAdd(&hist[dst[e] >> 9], 1);
  __syncthreads();
  int c = hist[tid];
  if (c > 0) base_[tid] = atomicAdd(&gcur[tid], c);
  hist[tid] = 0;
  __syncthreads();
  for (int e = e0 + tid; e < e1; e += 256) {
    int d = dst[e];
    int b = d >> 9;
    int r = atomicAdd(&hist[b], 1);
    pairs[base_[b] + r] = (u32)src[e] | ((u32)(d & 511) << 17);
  }
}

// D5: per-bucket CSR fill, cursors in LDS
__global__ __launch_bounds__(256) void fill2_k(
    const u32* __restrict__ pairs, const int* __restrict__ offs,
    int* __restrict__ col, int N) {
  __shared__ int cur[512];
  const int b = blockIdx.x;
  const int n0 = b << 9;
  const int n1 = min(N, n0 + 512);
  const int tid = threadIdx.x;
  for (int i = tid; i < n1 - n0; i += 256) cur[i] = offs[n0 + i];
  __syncthreads();
  const int e0 = offs[n0], e1 = offs[n1];
  for (int e = e0 + tid; e < e1; e += 256) {
    u32 pr = pairs[e];
    int p = atomicAdd(&cur[pr >> 17], 1);
    col[p] = (int)(pr & 0x1FFFFu);
  }
}

// D6..D8: fused layer = SpMM gather + W2 GEMM + res/LN/ReLU + next GEMM.
// FINAL==0: write h; phase3 = y @ W1next -> msc_out (inv-scaled).
// FINAL==1: no h write; out-LN in-register; phase3 = z @ Wout -> d_out (fp32).
template <int FINAL>
__global__ __launch_bounds__(256) void layer_fused_k(
    const uint4* __restrict__ mscin, const int* __restrict__ offs,
    const int* __restrict__ col, const float* __restrict__ inv,
    const u16* __restrict__ pW2, const float* __restrict__ b2,
    u32* __restrict__ h, const float* __restrict__ g1,
    const float* __restrict__ lb1,
    const u16* __restrict__ pWn, const float* __restrict__ bn,
    void* __restrict__ outv, const float* __restrict__ og,
    const float* __restrict__ ob, int N) {
  __shared__ u16 xs[32][136];
  __shared__ float cs[16][132];
  const int tid = threadIdx.x;
  const int lane = tid & 63, wid = tid >> 6;
  const int row0 = blockIdx.x * 32;
  const int rgrp = lane >> 4, c = lane & 15;

  // ---- phase 1: gather (reduce-free, MLP 8) ----
#pragma unroll
  for (int p = 0; p < 2; ++p) {
    const int lrow = wid * 8 + p * 4 + rgrp;
    const int d = row0 + lrow;
    const int s0 = offs[d], s1 = offs[d + 1];
    const int last = s1 - 1;
    float2 a0 = {0.f, 0.f}, a1 = {0.f, 0.f}, a2 = {0.f, 0.f}, a3 = {0.f, 0.f};
    for (int k = s0; k < s1; k += 8) {
      int sv[8];
#pragma unroll
      for (int j = 0; j < 8; ++j) sv[j] = col[min(k + j, last)];
      uint4 rv[8];
#pragma unroll
      for (int j = 0; j < 8; ++j) rv[j] = mscin[(size_t)sv[j] * 16 + c];
#pragma unroll
      for (int j = 0; j < 8; ++j) {
        float m = (k + j < s1) ? 1.f : 0.f;
        a0.x = fmaf(m, bflo(rv[j].x), a0.x); a0.y = fmaf(m, bfhi(rv[j].x), a0.y);
        a1.x = fmaf(m, bflo(rv[j].y), a1.x); a1.y = fmaf(m, bfhi(rv[j].y), a1.y);
        a2.x = fmaf(m, bflo(rv[j].z), a2.x); a2.y = fmaf(m, bfhi(rv[j].z), a2.y);
        a3.x = fmaf(m, bflo(rv[j].w), a3.x); a3.y = fmaf(m, bfhi(rv[j].w), a3.y);
      }
    }
    uint4 r = mscin[(size_t)d * 16 + c];   // self loop
    float iv = inv[d];
    uint4 o;
    o.x = pack2((a0.x + bflo(r.x)) * iv, (a0.y + bfhi(r.x)) * iv);
    o.y = pack2((a1.x + bflo(r.y)) * iv, (a1.y + bfhi(r.y)) * iv);
    o.z = pack2((a2.x + bflo(r.z)) * iv, (a2.y + bfhi(r.z)) * iv);
    o.w = pack2((a3.x + bflo(r.w)) * iv, (a3.y + bfhi(r.w)) * iv);
    *(uint4*)&xs[lrow][c * 8] = o;
  }
  __syncthreads();

  // ---- phase 2: W2 MFMA ----
  const int m0  = (wid >> 1) << 4;
  const int ntb = (wid & 1) << 2;
  f32x4 acc[4];
#pragma unroll
  for (int t = 0; t < 4; ++t) acc[t] = (f32x4){0.f, 0.f, 0.f, 0.f};
  MFMA128_FROM_XS(acc, (const bf16x8*)pW2);

  // ---- epilogue: bias + residual + LN + ReLU (y -> h and/or xs) ----
  const int cb = lane & 15;
  const int rg = (lane >> 4) << 2;
  float2 gg = *(const float2*)&g1[lane * 2];
  float2 bb = *(const float2*)&lb1[lane * 2];
  float2 ogg, obb;
  if constexpr (FINAL) {
    ogg = *(const float2*)&og[lane * 2];
    obb = *(const float2*)&ob[lane * 2];
  }
#pragma unroll
  for (int hh = 0; hh < 2; ++hh) {
    __syncthreads();
    if ((m0 >> 4) == hh) {
#pragma unroll
      for (int t = 0; t < 4; ++t) {
        int colm = (ntb + t) * 16 + cb;
        float bv = b2[colm];
#pragma unroll
        for (int r = 0; r < 4; ++r) cs[rg + r][colm] = acc[t][r] + bv;
      }
    }
    __syncthreads();
    for (int rr = 0; rr < 4; ++rr) {
      int lr = wid * 4 + rr;
      int r = hh * 16 + lr;
      int gr = row0 + r;
      float2 t2 = *(const float2*)&cs[lr][lane * 2];
      u32 hv = h[(size_t)gr * 64 + lane];
      float tx = t2.x + bflo(hv), ty = t2.y + bfhi(hv);
      float mean = wred(tx + ty) * (1.f / 128.f);
      float dx = tx - mean, dy = ty - mean;
      float var = wred(dx * dx + dy * dy) * (1.f / 128.f);
      float rstd = rsqrtf(var + 1e-5f);
      float y0 = fmaxf(dx * rstd * gg.x + bb.x, 0.f);
      float y1 = fmaxf(dy * rstd * gg.y + bb.y, 0.f);
      if constexpr (!FINAL) {
        u32 pk = pack2(y0, y1);
        h[(size_t)gr * 64 + lane] = pk;
        *(u32*)&xs[r][lane * 2] = pk;
      } else {
        float m2 = wred(y0 + y1) * (1.f / 128.f);
        float dx2 = y0 - m2, dy2 = y1 - m2;
        float v2 = wred(dx2 * dx2 + dy2 * dy2) * (1.f / 128.f);
        float rs2 = rsqrtf(v2 + 1e-5f);
        *(u32*)&xs[r][lane * 2] =
            pack2(dx2 * rs2 * ogg.x + obb.x, dy2 * rs2 * ogg.y + obb.y);
      }
    }
  }
  __syncthreads();

  // ---- phase 3 ----
  if constexpr (!FINAL) {
    f32x4 acc2[4];
#pragma unroll
    for (int t = 0; t < 4; ++t) acc2[t] = (f32x4){0.f, 0.f, 0.f, 0.f};
    MFMA128_FROM_XS(acc2, (const bf16x8*)pWn);
    u16* Y = (u16*)outv;
    float iv4[4];
#pragma unroll
    for (int r = 0; r < 4; ++r) iv4[r] = inv[row0 + m0 + rg + r];
#pragma unroll
    for (int t = 0; t < 4; ++t) {
      int colm = (ntb + t) * 16 + cb;
      float bv = bn[colm];
#pragma unroll
      for (int r = 0; r < 4; ++r) {
        int gr = row0 + m0 + rg + r;
        Y[(size_t)gr * 128 + colm] = f2bf((acc2[t][r] + bv) * iv4[r]);
      }
    }
  } else {
    const int m0b = (wid & 1) << 4;
    const int ntbb = (wid >> 1) << 1;
    const int arb = m0b + (lane & 15);
    const int akb = (lane >> 4) << 2;
    f32x4 acc2[2];
#pragma unroll
    for (int t = 0; t < 2; ++t) acc2[t] = (f32x4){0.f, 0.f, 0.f, 0.f};
    const bf16x8* Bp = (const bf16x8*)pWn;
#pragma unroll
    for (int kc = 0; kc < 4; ++kc) {
      u16x4 lo = *(const u16x4*)&xs[arb][kc * 32 + akb];
      u16x4 hi = *(const u16x4*)&xs[arb][kc * 32 + akb + 16];
      u16x8 av;
#pragma unroll
      for (int j = 0; j < 4; ++j) { av[j] = lo[j]; av[j + 4] = hi[j]; }
      bf16x8 a = __builtin_bit_cast(bf16x8, av);
#pragma unroll
      for (int t = 0; t < 2; ++t) {
        bf16x8 b = Bp[(kc * 4 + ntbb + t) * 64 + lane];
        acc2[t] = __builtin_amdgcn_mfma_f32_16x16x32_bf16(a, b, acc2[t], 0, 0, 0);
      }
    }
    float* Y = (float*)outv;
#pragma unroll
    for (int t = 0; t < 2; ++t) {
      int colo = (ntbb + t) * 16 + cb;
      float bv = bn[colo];
#pragma unroll
      for (int r = 0; r < 4; ++r) {
        int gr = row0 + m0b + rg + r;
        Y[(size_t)gr * 64 + colo] = acc2[t][r] + bv;
      }
    }
  }
}

// ---------------------------------------------------------------------------
extern "C" void kernel_launch(void* const* d_in, const int* in_sizes, int n_in,
                              void* d_out, int out_size, void* d_ws, size_t ws_size,
                              hipStream_t stream) {
  (void)n_in; (void)out_size; (void)ws_size;
  const float* x      = (const float*)d_in[0];
  const int*   eidx   = (const int*)d_in[1];
  const float* degree = (const float*)d_in[2];
  const float* Win    = (const float*)d_in[3];
  const float* b_in   = (const float*)d_in[4];
  const float* W1     = (const float*)d_in[5];
  const float* b1     = (const float*)d_in[6];
  const float* W2     = (const float*)d_in[7];
  const float* b2     = (const float*)d_in[8];
  const float* ln_g   = (const float*)d_in[9];
  const float* ln_b   = (const float*)d_in[10];
  const float* out_g  = (const float*)d_in[11];
  const float* out_b  = (const float*)d_in[12];
  const float* Wout   = (const float*)d_in[13];
  const float* b_out  = (const float*)d_in[14];

  const int N = in_sizes[0] / 128;
  const int E = in_sizes[1] / 2;
  const int* esrc = eidx;
  const int* edst = eidx + E;

  char* p = (char*)d_ws;
  auto alloc = [&](size_t bytes) {
    char* q = p;
    p += (bytes + 255) & ~(size_t)255;
    return q;
  };
  float* inv    = (float*)alloc((size_t)N * 4);
  int*   offs   = (int*)alloc(((size_t)N + 1) * 4);
  int*   gcur   = (int*)alloc(256 * 4);
  int*   bsum   = (int*)alloc(1024 * 4);
  int*   col    = (int*)alloc((size_t)E * 4);
  u32*   pairs  = (u32*)alloc((size_t)E * 4);
  u32*   h      = (u32*)alloc((size_t)N * 128 * 2);     // bf16 residual
  u32*   mscA   = (u32*)alloc((size_t)N * 128 * 2);     // bf16 ping
  u32*   mscB   = (u32*)alloc((size_t)N * 128 * 2);     // bf16 pong
  u16*   pWin   = (u16*)alloc(4 * 8 * 64 * 8 * 2);
  u16*   pWout  = (u16*)alloc(4 * 4 * 64 * 8 * 2);
  u16*   pW1    = (u16*)alloc(3 * 4 * 8 * 64 * 8 * 2);
  u16*   pW2    = (u16*)alloc(3 * 4 * 8 * 64 * 8 * 2);

  const int nb = (N + 255) / 256;              // scan blocks (<=512 req'd)
  const int NB = (N + 511) / 512;              // dst buckets
  const int gemmGrid = (N + 31) / 32;          // 3125
  const int saGrid = (N + 256) / 256;

  // D1: degree scan + inv + weight packing
  d1_scan_pack_k<<<nb + 60, 256, 0, stream>>>(
      degree, offs, bsum, inv, N, nb,
      Win, W1, W2, Wout, pWin, pW1, pW2, pWout);
  // D2: x@Win+ReLU -> h, y@W1(l0) -> mscA  (+ bsum scan)
  in_scale_k<<<gemmGrid + 1, 256, 0, stream>>>(
      x, pWin, b_in, pW1, b1, inv, h, (u16*)mscA, N, bsum, nb);
  // D3: offs finalize
  scan_add_k<<<saGrid, 256, 0, stream>>>(offs, bsum, gcur, N, E);
  // D4/D5: edge bucket-scatter, CSR fill
  scatter_k<<<(E + 8191) / 8192, 256, 0, stream>>>(esrc, edst, gcur, pairs, E);
  fill2_k<<<NB, 256, 0, stream>>>(pairs, offs, col, N);

  // D6: layer 0  (mscA -> h, mscB)
  layer_fused_k<0><<<gemmGrid, 256, 0, stream>>>(
      (const uint4*)mscA, offs, col, inv, pW2, b2, h, ln_g, ln_b,
      pW1 + 16384, b1 + 128, mscB, nullptr, nullptr, N);
  // D7: layer 1  (mscB -> h, mscA)
  layer_fused_k<0><<<gemmGrid, 256, 0, stream>>>(
      (const uint4*)mscB, offs, col, inv, pW2 + 16384, b2 + 128, h,
      ln_g + 128, ln_b + 128, pW1 + 32768, b1 + 256, mscA, nullptr, nullptr, N);
  // D8: layer 2 + out-LN + Wout  (mscA -> d_out)
  layer_fused_k<1><<<gemmGrid, 256, 0, stream>>>(
      (const uint4*)mscA, offs, col, inv, pW2 + 32768, b2 + 256, h,
      ln_g + 256, ln_b + 256, pWout, b_out, d_out, out_g, out_b, N);
}